// Round 3
// baseline (515.152 us; speedup 1.0000x reference)
//
#include <hip/hip_runtime.h>
#include <stdint.h>

#define EPSV 1e-5f

typedef __attribute__((ext_vector_type(8))) short short8;
typedef __attribute__((ext_vector_type(4))) float f32x4;
typedef __bf16 bf16x8 __attribute__((ext_vector_type(8)));

__device__ __forceinline__ unsigned short f2bf(float f) {
  union { float f; unsigned int u; } v; v.f = f;
  unsigned int r = (v.u + 0x7FFFu + ((v.u >> 16) & 1u)) >> 16;
  return (unsigned short)r;
}
__device__ __forceinline__ float bf2f(unsigned short h) {
  union { unsigned int u; float f; } v; v.u = ((unsigned int)h) << 16;
  return v.f;
}

__device__ __forceinline__ f32x4 mfma16(bf16x8 a, bf16x8 b, f32x4 c) {
  return __builtin_amdgcn_mfma_f32_16x16x32_bf16(a, b, c, 0, 0, 0);
}

#define GLOAD16(g, l)                                                          \
  __builtin_amdgcn_global_load_lds(                                            \
      (const __attribute__((address_space(1))) void*)(g),                      \
      (__attribute__((address_space(3))) void*)(l), 16, 0, 0)

// ---------------- GroupNorm stats: per-sample sum / sumsq ----------------
__global__ __launch_bounds__(256) void k_gn_stats(const float* __restrict__ x,
                                                  float* __restrict__ stats) {
  int b = blockIdx.x >> 6, chunk = blockIdx.x & 63;
  const float4* xp = (const float4*)(x + ((size_t)b << 20) + (size_t)chunk * 16384);
  int t = threadIdx.x;
  float s = 0.f, q = 0.f;
#pragma unroll
  for (int i = 0; i < 16; ++i) {
    float4 v = xp[i * 256 + t];
    s += v.x + v.y + v.z + v.w;
    q += v.x * v.x + v.y * v.y + v.z * v.z + v.w * v.w;
  }
#pragma unroll
  for (int m = 1; m <= 32; m <<= 1) { s += __shfl_xor(s, m); q += __shfl_xor(q, m); }
  __shared__ float ls[8];
  int w = t >> 6, l = t & 63;
  if (l == 0) { ls[w * 2] = s; ls[w * 2 + 1] = q; }
  __syncthreads();
  if (t == 0) {
    float S = ls[0] + ls[2] + ls[4] + ls[6];
    float Q = ls[1] + ls[3] + ls[5] + ls[7];
    atomicAdd(&stats[b * 2], S);
    atomicAdd(&stats[b * 2 + 1], Q);
  }
}

// ---------- normalize + NCHW->padded-NHWC transpose (bf16) ----------
__global__ __launch_bounds__(256) void k_gn_norm(const float* __restrict__ x,
                                                 const float* __restrict__ stats,
                                                 const float* __restrict__ g,
                                                 const float* __restrict__ bb,
                                                 unsigned short* __restrict__ xnp) {
  __shared__ float tile[64][65];
  int pt = blockIdx.x;  // image row y (64 pixels)
  int ct = blockIdx.y;  // ci tile (4)
  int b = blockIdx.z;
  int t = threadIdx.x, tr = t >> 6, tc = t & 63;
  const float* xb = x + ((size_t)b << 20) + (size_t)(ct * 64) * 4096 + pt * 64;
#pragma unroll
  for (int i = 0; i < 16; ++i) {
    int r = i * 4 + tr;
    tile[r][tc] = xb[(size_t)r * 4096 + tc];
  }
  __syncthreads();
  float mu = stats[b * 2] * (1.f / 1048576.f);
  float var = stats[b * 2 + 1] * (1.f / 1048576.f) - mu * mu;
  float istd = rsqrtf(var + EPSV);
  float gg = g[ct * 64 + tc] * istd;
  float bv = bb[ct * 64 + tc];
  unsigned short* out = xnp + (((size_t)b * 66 + (pt + 1)) * 66 + 1) * 256 + ct * 64 + tc;
#pragma unroll
  for (int i = 0; i < 16; ++i) {
    int pcol = i * 4 + tr;
    float v = (tile[tc][pcol] - mu) * gg + bv;
    out[(size_t)pcol * 256] = f2bf(v);
  }
}

// ------------- weight prep: w_in -> wt[tap][co][ci] bf16, BN folded -------------
__global__ __launch_bounds__(256) void k_prep_wt(const float* __restrict__ w_in,
                                                 const float* __restrict__ bg,
                                                 const float* __restrict__ bv,
                                                 unsigned short* __restrict__ wt) {
  int idx = blockIdx.x * 256 + threadIdx.x;
  if (idx >= 9 * 384 * 256) return;
  int tap = idx / 98304;
  int rem = idx - tap * 98304;
  int co = rem >> 8, ci = rem & 255;
  float s = bg[co] * rsqrtf(bv[co] + EPSV);
  wt[idx] = f2bf(w_in[(size_t)(co * 256 + ci) * 9 + tap] * s);
}

__global__ __launch_bounds__(256) void k_prep_misc(
    const float* w_out, const float* og, const float* ob, const float* om, const float* ov,
    const float* big, const float* bib, const float* bim, const float* biv,
    const float* w_k, const float* kg, const float* kb, const float* km, const float* kvv,
    const float* w_v, const float* vg, const float* vb, const float* vm, const float* vvv,
    unsigned short* wo2, float* bias_in, float* bias_out,
    float* wkf, float* bias_k, float* wvf, float* bias_v) {
  int idx = blockIdx.x * 256 + threadIdx.x;
  if (idx < 65536) {
    int co = idx >> 8;
    float s = og[co] * rsqrtf(ov[co] + EPSV);
    wo2[idx] = f2bf(w_out[idx] * s);
    return;
  }
  idx -= 65536;
  if (idx < 384) {
    float s = big[idx] * rsqrtf(biv[idx] + EPSV);
    bias_in[idx] = bib[idx] - bim[idx] * s;
    return;
  }
  idx -= 384;
  if (idx < 256) {
    float s = og[idx] * rsqrtf(ov[idx] + EPSV);
    bias_out[idx] = ob[idx] - om[idx] * s;
    return;
  }
  idx -= 256;
  if (idx < 64) {
    float s = kg[idx] * rsqrtf(kvv[idx] + EPSV);
#pragma unroll
    for (int tp = 0; tp < 4; ++tp) wkf[idx * 4 + tp] = w_k[idx * 4 + tp] * s;
    bias_k[idx] = kb[idx] - km[idx] * s;
    return;
  }
  idx -= 64;
  if (idx < 128) {
    float s = vg[idx] * rsqrtf(vvv[idx] + EPSV);
#pragma unroll
    for (int tp = 0; tp < 4; ++tp) wvf[idx * 4 + tp] = w_v[idx * 4 + tp] * s;
    bias_v[idx] = vb[idx] - vm[idx] * s;
    return;
  }
}

// ---------------- conv3x3 implicit GEMM: y[b][p][co] bf16 ----------------
// D[p][co], per-batch M=4096,N=384,K=9*256. Tile 128x128, 4 waves 2x2.
__global__ __launch_bounds__(256) void k_conv3(const unsigned short* __restrict__ xnp,
                                               const unsigned short* __restrict__ wt,
                                               const float* __restrict__ bias_in,
                                               unsigned short* __restrict__ y) {
  int pt = blockIdx.x, cot = blockIdx.y, b = blockIdx.z;
  int p0 = pt * 128, co0 = cot * 128;
  __shared__ alignas(16) unsigned short As[128 * 64];
  __shared__ alignas(16) unsigned short Bs[128 * 64];
  int t = threadIdx.x, w = t >> 6, l = t & 63;
  int rr = t >> 3, c8 = (t & 7) * 8;
  int lg = l >> 4, lr = l & 15;

  int baseA[4];
#pragma unroll
  for (int i = 0; i < 4; ++i) {
    int p = p0 + i * 32 + rr;
    int yy = p >> 6, xx = p & 63;
    baseA[i] = ((b * 66 + yy) * 66 + xx) * 256 + c8;
  }
  int baseB = (co0 + rr) * 256 + c8;

  f32x4 acc[4][4];
#pragma unroll
  for (int i = 0; i < 4; ++i)
#pragma unroll
    for (int j = 0; j < 4; ++j) acc[i][j] = f32x4{0.f, 0.f, 0.f, 0.f};

  int wr = (w >> 1) * 64, wc = (w & 1) * 64;

  for (int tap = 0; tap < 9; ++tap) {
    int aoff = ((tap / 3) * 66 + (tap % 3)) * 256;
#pragma unroll 1
    for (int kc = 0; kc < 4; ++kc) {
      int ci0 = kc * 64;
      __syncthreads();
#pragma unroll
      for (int i = 0; i < 4; ++i) {
        GLOAD16(xnp + baseA[i] + aoff + ci0, &As[(i * 32 + w * 8) * 64]);
        GLOAD16(wt + baseB + tap * 98304 + i * 8192 + ci0, &Bs[(i * 32 + w * 8) * 64]);
      }
      __syncthreads();
      bf16x8 af[4][2], bf[4][2];
#pragma unroll
      for (int mt = 0; mt < 4; ++mt)
#pragma unroll
        for (int k2 = 0; k2 < 2; ++k2) {
          af[mt][k2] = *(const bf16x8*)&As[(wr + mt * 16 + lr) * 64 + k2 * 32 + lg * 8];
          bf[mt][k2] = *(const bf16x8*)&Bs[(wc + mt * 16 + lr) * 64 + k2 * 32 + lg * 8];
        }
#pragma unroll
      for (int mt = 0; mt < 4; ++mt)
#pragma unroll
        for (int nt = 0; nt < 4; ++nt) {
          acc[mt][nt] = mfma16(af[mt][0], bf[nt][0], acc[mt][nt]);
          acc[mt][nt] = mfma16(af[mt][1], bf[nt][1], acc[mt][nt]);
        }
    }
  }
  float bias[4];
  int coBase = co0 + wc;
#pragma unroll
  for (int nt = 0; nt < 4; ++nt) bias[nt] = bias_in[coBase + nt * 16 + lr];
#pragma unroll
  for (int mt = 0; mt < 4; ++mt) {
    int p = p0 + wr + mt * 16 + lg * 4;
#pragma unroll
    for (int r = 0; r < 4; ++r) {
      size_t rowoff = ((size_t)(b * 4096 + p + r)) * 384;
#pragma unroll
      for (int nt = 0; nt < 4; ++nt) {
        int co = coBase + nt * 16 + lr;
        float v = acc[mt][nt][r] + bias[nt];
        if (co >= 256) v = fmaxf(v, 0.f);  // pre-ReLU the u channels
        y[rowoff + co] = f2bf(v);
      }
    }
  }
}

// ------------- depthwise 2x2 stride-2 convs, LDS-tiled -------------
// block = (b, my): stages y pixels [2my*64 .. 2my*64+127], channels 64..255
// into LDS, computes kk[b][m][c] and vv[b][cv][m] (vv via LDS transpose).
__global__ __launch_bounds__(256) void k_kv(const unsigned short* __restrict__ y,
                                            const float* __restrict__ wkf, const float* __restrict__ bias_k,
                                            const float* __restrict__ wvf, const float* __restrict__ bias_v,
                                            unsigned short* __restrict__ kk, unsigned short* __restrict__ vv) {
  constexpr int LDW = 200;  // padded row stride (elements), 400B: 16B-aligned rows
  __shared__ unsigned short ty[128 * LDW];
  __shared__ unsigned short vt[128 * 33];
  int b = blockIdx.x >> 5, my = blockIdx.x & 31;
  int t = threadIdx.x;
  const unsigned short* ybase = y + ((size_t)(b * 4096 + my * 128)) * 384 + 64;
#pragma unroll
  for (int j = 0; j < 12; ++j) {
    int idx = j * 256 + t;          // 3072 = 128 rows * 24 vec8
    int row = idx / 24, c8 = idx - row * 24;
    bf16x8 v = *(const bf16x8*)&ybase[(size_t)row * 384 + c8 * 8];
    *(bf16x8*)&ty[row * LDW + c8 * 8] = v;
  }
  __syncthreads();

  // ---- k path: thread (c = t&63, wave w covers one mx per pass) ----
  {
    int c = t & 63, wq = t >> 6;
    float wk0 = wkf[c * 4 + 0], wk1 = wkf[c * 4 + 1];
    float wk2 = wkf[c * 4 + 2], wk3 = wkf[c * 4 + 3];
    float bk = bias_k[c];
#pragma unroll
    for (int pass = 0; pass < 8; ++pass) {
      int mx = pass * 4 + wq;
      int r0 = 2 * mx, r1 = 2 * mx + 1;
      float a = bk;
      a += bf2f(ty[r0 * LDW + c]) * wk0;
      a += bf2f(ty[(r0 + 1) * LDW + c]) * wk1;
      a += bf2f(ty[(64 + r0) * LDW + c]) * wk2;
      a += bf2f(ty[(64 + r1) * LDW + c]) * wk3;
      kk[((size_t)(b * 1024 + my * 32 + mx)) * 64 + c] = f2bf(a);
    }
  }

  // ---- v path: thread (cv = t&127, mxh = t>>7), results into vt ----
  {
    int cv = t & 127, mxh = t >> 7;
    float wv0 = wvf[cv * 4 + 0], wv1 = wvf[cv * 4 + 1];
    float wv2 = wvf[cv * 4 + 2], wv3 = wvf[cv * 4 + 3];
    float bv = bias_v[cv];
    int col = 64 + cv;  // v channels at tile cols 64..191
#pragma unroll
    for (int pass = 0; pass < 16; ++pass) {
      int mx = pass * 2 + mxh;
      int r0 = 2 * mx, r1 = 2 * mx + 1;
      float a = bv;
      a += bf2f(ty[r0 * LDW + col]) * wv0;
      a += bf2f(ty[r1 * LDW + col]) * wv1;
      a += bf2f(ty[(64 + r0) * LDW + col]) * wv2;
      a += bf2f(ty[(64 + r1) * LDW + col]) * wv3;
      vt[cv * 33 + mx] = f2bf(a);
    }
  }
  __syncthreads();
  // ---- vt -> vv coalesced: thread (mx = t&31, cvq = t>>5) ----
  {
    int mx = t & 31, cvq = t >> 5;
#pragma unroll
    for (int i = 0; i < 16; ++i) {
      int cv = i * 8 + cvq;
      vv[((size_t)(b * 128 + cv)) * 1024 + my * 32 + mx] = vt[cv * 33 + mx];
    }
  }
}

// ---------------- flash attention; writes relu(o) into y channels 128..255 ----------------
__global__ __launch_bounds__(256) void k_attn(unsigned short* __restrict__ y,
                                              const unsigned short* __restrict__ kk,
                                              const unsigned short* __restrict__ vvb) {
  int blk = blockIdx.x;
  int b = blk >> 5, ntile = blk & 31;
  int t = threadIdx.x, w = t >> 6, l = t & 63;
  int nq0 = ntile * 128 + w * 32;
  int lg = l >> 4, lr = l & 15;
  __shared__ alignas(16) unsigned short P[4][2][16][64];
  const float SC = 0.125f * 1.44269504f;  // scale * log2(e)

  union { short8 s; bf16x8 b; } uo;
#pragma unroll
  for (int i = 0; i < 8; ++i) uo.s[i] = (short)0x3F80;  // bf16 1.0
  bf16x8 ones = uo.b;

  bf16x8 qf[2][2];
#pragma unroll
  for (int qt = 0; qt < 2; ++qt)
#pragma unroll
    for (int c = 0; c < 2; ++c)
      qf[qt][c] = *(const bf16x8*)&y[((size_t)(b * 4096 + nq0 + qt * 16 + lr)) * 384 + c * 32 + lg * 8];

  f32x4 oa[2][8];
#pragma unroll
  for (int qt = 0; qt < 2; ++qt)
#pragma unroll
    for (int tt = 0; tt < 8; ++tt) oa[qt][tt] = f32x4{0.f, 0.f, 0.f, 0.f};
  float mi[2][4], li[2][4];
#pragma unroll
  for (int qt = 0; qt < 2; ++qt)
#pragma unroll
    for (int r = 0; r < 4; ++r) { mi[qt][r] = -1e30f; li[qt][r] = 0.f; }

  for (int m0 = 0; m0 < 1024; m0 += 64) {
    bf16x8 kf[4][2];
#pragma unroll
    for (int mt = 0; mt < 4; ++mt)
#pragma unroll
      for (int c = 0; c < 2; ++c)
        kf[mt][c] = *(const bf16x8*)&kk[((size_t)(b * 1024 + m0 + mt * 16 + lr)) * 64 + c * 32 + lg * 8];

#pragma unroll
    for (int qt = 0; qt < 2; ++qt) {
      f32x4 s[4];
#pragma unroll
      for (int mt = 0; mt < 4; ++mt) {
        f32x4 z = f32x4{0.f, 0.f, 0.f, 0.f};
        z = mfma16(qf[qt][0], kf[mt][0], z);
        z = mfma16(qf[qt][1], kf[mt][1], z);
        s[mt] = z;
      }
      float rm[4];
#pragma unroll
      for (int r = 0; r < 4; ++r) {
        s[0][r] *= SC; s[1][r] *= SC; s[2][r] *= SC; s[3][r] *= SC;
        rm[r] = fmaxf(fmaxf(s[0][r], s[1][r]), fmaxf(s[2][r], s[3][r]));
      }
#pragma unroll
      for (int msk = 1; msk <= 8; msk <<= 1)
#pragma unroll
        for (int r = 0; r < 4; ++r) rm[r] = fmaxf(rm[r], __shfl_xor(rm[r], msk));
      // defer-max: only rescale when some row max grew
      bool grow = (rm[0] > mi[qt][0]) | (rm[1] > mi[qt][1]) |
                  (rm[2] > mi[qt][2]) | (rm[3] > mi[qt][3]);
      if (__any(grow)) {
#pragma unroll
        for (int r = 0; r < 4; ++r) {
          float nm = fmaxf(mi[qt][r], rm[r]);
          float corr = exp2f(mi[qt][r] - nm);
          mi[qt][r] = nm;
          li[qt][r] *= corr;
#pragma unroll
          for (int tt = 0; tt < 8; ++tt) oa[qt][tt][r] *= corr;
        }
      }
#pragma unroll
      for (int mt = 0; mt < 4; ++mt)
#pragma unroll
        for (int r = 0; r < 4; ++r) {
          float e = exp2f(s[mt][r] - mi[qt][r]);
          P[w][qt][lg * 4 + r][mt * 16 + lr] = f2bf(e);
        }
    }
    __builtin_amdgcn_wave_barrier();
    bf16x8 pf[2][2];
#pragma unroll
    for (int qt = 0; qt < 2; ++qt)
#pragma unroll
      for (int mc = 0; mc < 2; ++mc)
        pf[qt][mc] = *(const bf16x8*)&P[w][qt][lr][mc * 32 + lg * 8];
    // row-sums via MFMA against ones (replaces shuffle reduce)
#pragma unroll
    for (int qt = 0; qt < 2; ++qt) {
      f32x4 zz = f32x4{0.f, 0.f, 0.f, 0.f};
      zz = mfma16(pf[qt][0], ones, zz);
      zz = mfma16(pf[qt][1], ones, zz);
#pragma unroll
      for (int r = 0; r < 4; ++r) li[qt][r] += zz[r];
    }
#pragma unroll
    for (int tt = 0; tt < 8; ++tt) {
      bf16x8 vf0 = *(const bf16x8*)&vvb[((size_t)(b * 128 + tt * 16 + lr)) * 1024 + m0 + lg * 8];
      bf16x8 vf1 = *(const bf16x8*)&vvb[((size_t)(b * 128 + tt * 16 + lr)) * 1024 + m0 + 32 + lg * 8];
#pragma unroll
      for (int qt = 0; qt < 2; ++qt) {
        oa[qt][tt] = mfma16(pf[qt][0], vf0, oa[qt][tt]);
        oa[qt][tt] = mfma16(pf[qt][1], vf1, oa[qt][tt]);
      }
    }
  }
#pragma unroll
  for (int qt = 0; qt < 2; ++qt)
#pragma unroll
    for (int r = 0; r < 4; ++r) {
      float inv = 1.f / li[qt][r];
      int p = nq0 + qt * 16 + lg * 4 + r;
#pragma unroll
      for (int tt = 0; tt < 8; ++tt) {
        float v = oa[qt][tt][r] * inv;
        v = fmaxf(v, 0.f);  // pre-ReLU for conv1x1
        y[((size_t)(b * 4096 + p)) * 384 + 128 + tt * 16 + lr] = f2bf(v);
      }
    }
}

// ---------------- conv1x1 GEMM: out[b][co][p] f32 (NCHW) ----------------
__global__ __launch_bounds__(256) void k_conv1(const unsigned short* __restrict__ y,
                                               const unsigned short* __restrict__ wo2,
                                               const float* __restrict__ bias_out,
                                               float* __restrict__ out) {
  int ptile = blockIdx.x, cot = blockIdx.y, b = blockIdx.z;
  int p0 = ptile * 128, co0 = cot * 128;
  __shared__ alignas(16) unsigned short As[128 * 64];
  __shared__ alignas(16) unsigned short Bs[128 * 64];
  int t = threadIdx.x, w = t >> 6, l = t & 63;
  int rr = t >> 3, c8 = (t & 7) * 8;
  int lg = l >> 4, lr = l & 15;
  int baseA = (co0 + rr) * 256 + c8;
  size_t baseB = ((size_t)(b * 4096 + p0 + rr)) * 384 + 128 + c8;
  f32x4 acc[4][4];
#pragma unroll
  for (int i = 0; i < 4; ++i)
#pragma unroll
    for (int j = 0; j < 4; ++j) acc[i][j] = f32x4{0.f, 0.f, 0.f, 0.f};
  int wr = (w >> 1) * 64, wc = (w & 1) * 64;  // wr: co half, wc: p half
#pragma unroll 1
  for (int kc = 0; kc < 4; ++kc) {
    int ci0 = kc * 64;
    __syncthreads();
#pragma unroll
    for (int i = 0; i < 4; ++i) {
      GLOAD16(wo2 + baseA + i * 8192 + ci0, &As[(i * 32 + w * 8) * 64]);
      GLOAD16(y + baseB + (size_t)i * 32 * 384 + ci0, &Bs[(i * 32 + w * 8) * 64]);
    }
    __syncthreads();
    bf16x8 af[4][2], bf[4][2];
#pragma unroll
    for (int mt = 0; mt < 4; ++mt)
#pragma unroll
      for (int k2 = 0; k2 < 2; ++k2) {
        af[mt][k2] = *(const bf16x8*)&As[(wr + mt * 16 + lr) * 64 + k2 * 32 + lg * 8];
        bf[mt][k2] = *(const bf16x8*)&Bs[(wc + mt * 16 + lr) * 64 + k2 * 32 + lg * 8];
      }
#pragma unroll
    for (int mt = 0; mt < 4; ++mt)
#pragma unroll
      for (int nt = 0; nt < 4; ++nt) {
        acc[mt][nt] = mfma16(af[mt][0], bf[nt][0], acc[mt][nt]);
        acc[mt][nt] = mfma16(af[mt][1], bf[nt][1], acc[mt][nt]);
      }
  }
#pragma unroll
  for (int mt = 0; mt < 4; ++mt)
#pragma unroll
    for (int r = 0; r < 4; ++r) {
      int co = co0 + wr + mt * 16 + lg * 4 + r;
      float bv = bias_out[co];
      size_t obase = ((size_t)(b * 256 + co)) << 12;
#pragma unroll
      for (int nt = 0; nt < 4; ++nt) {
        int p = p0 + wc + nt * 16 + lr;
        out[obase + p] = acc[mt][nt][r] + bv;
      }
    }
}

// ---------------- host launch ----------------
static constexpr size_t pad256(size_t x) { return (x + 255) & ~(size_t)255; }

extern "C" void kernel_launch(void* const* d_in, const int* in_sizes, int n_in,
                              void* d_out, int out_size, void* d_ws, size_t ws_size,
                              hipStream_t stream) {
  const float* x      = (const float*)d_in[0];
  const float* gn_g   = (const float*)d_in[1];
  const float* gn_b   = (const float*)d_in[2];
  const float* w_in   = (const float*)d_in[3];
  const float* bin_g  = (const float*)d_in[4];
  const float* bin_b  = (const float*)d_in[5];
  const float* bin_m  = (const float*)d_in[6];
  const float* bin_v  = (const float*)d_in[7];
  const float* w_k    = (const float*)d_in[8];
  const float* bk_g   = (const float*)d_in[9];
  const float* bk_b   = (const float*)d_in[10];
  const float* bk_m   = (const float*)d_in[11];
  const float* bk_v   = (const float*)d_in[12];
  const float* w_v    = (const float*)d_in[13];
  const float* bv_g   = (const float*)d_in[14];
  const float* bv_b   = (const float*)d_in[15];
  const float* bv_m   = (const float*)d_in[16];
  const float* bv_v   = (const float*)d_in[17];
  const float* w_out  = (const float*)d_in[18];
  const float* bo_g   = (const float*)d_in[19];
  const float* bo_b   = (const float*)d_in[20];
  const float* bo_m   = (const float*)d_in[21];
  const float* bo_v   = (const float*)d_in[22];
  float* out = (float*)d_out;

  char* ws = (char*)d_ws;
  size_t off = 0;
  float*          stats   = (float*)(ws + off);          off += pad256(128);
  unsigned short* wt      = (unsigned short*)(ws + off); off += pad256((size_t)9 * 384 * 256 * 2);
  float*          bias_in = (float*)(ws + off);          off += pad256(384 * 4);
  unsigned short* wo2     = (unsigned short*)(ws + off); off += pad256(256 * 256 * 2);
  float*          bias_out= (float*)(ws + off);          off += pad256(256 * 4);
  float*          wkf     = (float*)(ws + off);          off += pad256(64 * 4 * 4);
  float*          bias_k  = (float*)(ws + off);          off += pad256(64 * 4);
  float*          wvf     = (float*)(ws + off);          off += pad256(128 * 4 * 4);
  float*          bias_v  = (float*)(ws + off);          off += pad256(128 * 4);
  unsigned short* xnp     = (unsigned short*)(ws + off); off += pad256((size_t)16 * 66 * 66 * 256 * 2);
  unsigned short* y       = (unsigned short*)(ws + off); off += pad256((size_t)16 * 4096 * 384 * 2);
  unsigned short* kk      = (unsigned short*)(ws + off); off += pad256((size_t)16 * 1024 * 64 * 2);
  unsigned short* vv      = (unsigned short*)(ws + off); off += pad256((size_t)16 * 128 * 1024 * 2);
  (void)ws_size; (void)out_size; (void)n_in; (void)in_sizes;

  hipMemsetAsync(stats, 0, 256, stream);
  hipMemsetAsync(xnp, 0, (size_t)16 * 66 * 66 * 256 * 2, stream);

  k_gn_stats<<<1024, 256, 0, stream>>>(x, stats);
  k_prep_wt<<<3456, 256, 0, stream>>>(w_in, bin_g, bin_v, wt);
  k_prep_misc<<<260, 256, 0, stream>>>(w_out, bo_g, bo_b, bo_m, bo_v,
                                       bin_g, bin_b, bin_m, bin_v,
                                       w_k, bk_g, bk_b, bk_m, bk_v,
                                       w_v, bv_g, bv_b, bv_m, bv_v,
                                       wo2, bias_in, bias_out, wkf, bias_k, wvf, bias_v);
  k_gn_norm<<<dim3(64, 4, 16), 256, 0, stream>>>(x, stats, gn_g, gn_b, xnp);
  k_conv3<<<dim3(32, 3, 16), 256, 0, stream>>>(xnp, wt, bias_in, y);
  k_kv<<<512, 256, 0, stream>>>(y, wkf, bias_k, wvf, bias_v, kk, vv);
  k_attn<<<512, 256, 0, stream>>>(y, kk, vv);
  k_conv1<<<dim3(32, 2, 16), 256, 0, stream>>>(y, wo2, bias_out, out);
}

// Round 4
// 469.136 us; speedup vs baseline: 1.0981x; 1.0981x over previous
//
#include <hip/hip_runtime.h>
#include <stdint.h>

#define EPSV 1e-5f

typedef __attribute__((ext_vector_type(8))) short short8;
typedef __attribute__((ext_vector_type(4))) float f32x4;
typedef __bf16 bf16x8 __attribute__((ext_vector_type(8)));

__device__ __forceinline__ unsigned short f2bf(float f) {
  union { float f; unsigned int u; } v; v.f = f;
  unsigned int r = (v.u + 0x7FFFu + ((v.u >> 16) & 1u)) >> 16;
  return (unsigned short)r;
}
__device__ __forceinline__ float bf2f(unsigned short h) {
  union { unsigned int u; float f; } v; v.u = ((unsigned int)h) << 16;
  return v.f;
}

__device__ __forceinline__ f32x4 mfma16(bf16x8 a, bf16x8 b, f32x4 c) {
  return __builtin_amdgcn_mfma_f32_16x16x32_bf16(a, b, c, 0, 0, 0);
}

__device__ __forceinline__ unsigned cvt_pk_bf16(float lo, float hi) {
  unsigned r;
  asm("v_cvt_pk_bf16_f32 %0, %1, %2" : "=v"(r) : "v"(lo), "v"(hi));
  return r;
}

#define GLOAD16(g, l)                                                          \
  __builtin_amdgcn_global_load_lds(                                            \
      (const __attribute__((address_space(1))) void*)(g),                      \
      (__attribute__((address_space(3))) void*)(l), 16, 0, 0)

// ---------------- GroupNorm stats: per-sample sum / sumsq ----------------
__global__ __launch_bounds__(256) void k_gn_stats(const float* __restrict__ x,
                                                  float* __restrict__ stats) {
  int b = blockIdx.x >> 6, chunk = blockIdx.x & 63;
  const float4* xp = (const float4*)(x + ((size_t)b << 20) + (size_t)chunk * 16384);
  int t = threadIdx.x;
  float s = 0.f, q = 0.f;
#pragma unroll
  for (int i = 0; i < 16; ++i) {
    float4 v = xp[i * 256 + t];
    s += v.x + v.y + v.z + v.w;
    q += v.x * v.x + v.y * v.y + v.z * v.z + v.w * v.w;
  }
#pragma unroll
  for (int m = 1; m <= 32; m <<= 1) { s += __shfl_xor(s, m); q += __shfl_xor(q, m); }
  __shared__ float ls[8];
  int w = t >> 6, l = t & 63;
  if (l == 0) { ls[w * 2] = s; ls[w * 2 + 1] = q; }
  __syncthreads();
  if (t == 0) {
    float S = ls[0] + ls[2] + ls[4] + ls[6];
    float Q = ls[1] + ls[3] + ls[5] + ls[7];
    atomicAdd(&stats[b * 2], S);
    atomicAdd(&stats[b * 2 + 1], Q);
  }
}

// ---------- normalize + NCHW->padded-NHWC transpose (bf16) ----------
__global__ __launch_bounds__(256) void k_gn_norm(const float* __restrict__ x,
                                                 const float* __restrict__ stats,
                                                 const float* __restrict__ g,
                                                 const float* __restrict__ bb,
                                                 unsigned short* __restrict__ xnp) {
  __shared__ float tile[64][65];
  int pt = blockIdx.x;  // image row y (64 pixels)
  int ct = blockIdx.y;  // ci tile (4)
  int b = blockIdx.z;
  int t = threadIdx.x, tr = t >> 6, tc = t & 63;
  const float* xb = x + ((size_t)b << 20) + (size_t)(ct * 64) * 4096 + pt * 64;
#pragma unroll
  for (int i = 0; i < 16; ++i) {
    int r = i * 4 + tr;
    tile[r][tc] = xb[(size_t)r * 4096 + tc];
  }
  __syncthreads();
  float mu = stats[b * 2] * (1.f / 1048576.f);
  float var = stats[b * 2 + 1] * (1.f / 1048576.f) - mu * mu;
  float istd = rsqrtf(var + EPSV);
  float gg = g[ct * 64 + tc] * istd;
  float bv = bb[ct * 64 + tc];
  unsigned short* out = xnp + (((size_t)b * 66 + (pt + 1)) * 66 + 1) * 256 + ct * 64 + tc;
#pragma unroll
  for (int i = 0; i < 16; ++i) {
    int pcol = i * 4 + tr;
    float v = (tile[tc][pcol] - mu) * gg + bv;
    out[(size_t)pcol * 256] = f2bf(v);
  }
}

// ------------- weight prep: w_in -> wt[tap][co][ci] bf16, BN folded -------------
__global__ __launch_bounds__(256) void k_prep_wt(const float* __restrict__ w_in,
                                                 const float* __restrict__ bg,
                                                 const float* __restrict__ bv,
                                                 unsigned short* __restrict__ wt) {
  int idx = blockIdx.x * 256 + threadIdx.x;
  if (idx >= 9 * 384 * 256) return;
  int tap = idx / 98304;
  int rem = idx - tap * 98304;
  int co = rem >> 8, ci = rem & 255;
  float s = bg[co] * rsqrtf(bv[co] + EPSV);
  wt[idx] = f2bf(w_in[(size_t)(co * 256 + ci) * 9 + tap] * s);
}

__global__ __launch_bounds__(256) void k_prep_misc(
    const float* w_out, const float* og, const float* ob, const float* om, const float* ov,
    const float* big, const float* bib, const float* bim, const float* biv,
    const float* w_k, const float* kg, const float* kb, const float* km, const float* kvv,
    const float* w_v, const float* vg, const float* vb, const float* vm, const float* vvv,
    unsigned short* wo2, float* bias_in, float* bias_out,
    float* wkf, float* bias_k, float* wvf, float* bias_v) {
  int idx = blockIdx.x * 256 + threadIdx.x;
  if (idx < 65536) {
    int co = idx >> 8;
    float s = og[co] * rsqrtf(ov[co] + EPSV);
    wo2[idx] = f2bf(w_out[idx] * s);
    return;
  }
  idx -= 65536;
  if (idx < 384) {
    float s = big[idx] * rsqrtf(biv[idx] + EPSV);
    bias_in[idx] = bib[idx] - bim[idx] * s;
    return;
  }
  idx -= 384;
  if (idx < 256) {
    float s = og[idx] * rsqrtf(ov[idx] + EPSV);
    bias_out[idx] = ob[idx] - om[idx] * s;
    return;
  }
  idx -= 256;
  if (idx < 64) {
    float s = kg[idx] * rsqrtf(kvv[idx] + EPSV);
#pragma unroll
    for (int tp = 0; tp < 4; ++tp) wkf[idx * 4 + tp] = w_k[idx * 4 + tp] * s;
    bias_k[idx] = kb[idx] - km[idx] * s;
    return;
  }
  idx -= 64;
  if (idx < 128) {
    float s = vg[idx] * rsqrtf(vvv[idx] + EPSV);
#pragma unroll
    for (int tp = 0; tp < 4; ++tp) wvf[idx * 4 + tp] = w_v[idx * 4 + tp] * s;
    bias_v[idx] = vb[idx] - vm[idx] * s;
    return;
  }
}

// ---------------- conv3x3 implicit GEMM: y[b][p][co] bf16 ----------------
__global__ __launch_bounds__(256) void k_conv3(const unsigned short* __restrict__ xnp,
                                               const unsigned short* __restrict__ wt,
                                               const float* __restrict__ bias_in,
                                               unsigned short* __restrict__ y) {
  int pt = blockIdx.x, cot = blockIdx.y, b = blockIdx.z;
  int p0 = pt * 128, co0 = cot * 128;
  __shared__ alignas(16) unsigned short As[128 * 64];
  __shared__ alignas(16) unsigned short Bs[128 * 64];
  int t = threadIdx.x, w = t >> 6, l = t & 63;
  int rr = t >> 3, c8 = (t & 7) * 8;
  int lg = l >> 4, lr = l & 15;

  int baseA[4];
#pragma unroll
  for (int i = 0; i < 4; ++i) {
    int p = p0 + i * 32 + rr;
    int yy = p >> 6, xx = p & 63;
    baseA[i] = ((b * 66 + yy) * 66 + xx) * 256 + c8;
  }
  int baseB = (co0 + rr) * 256 + c8;

  f32x4 acc[4][4];
#pragma unroll
  for (int i = 0; i < 4; ++i)
#pragma unroll
    for (int j = 0; j < 4; ++j) acc[i][j] = f32x4{0.f, 0.f, 0.f, 0.f};

  int wr = (w >> 1) * 64, wc = (w & 1) * 64;

  for (int tap = 0; tap < 9; ++tap) {
    int aoff = ((tap / 3) * 66 + (tap % 3)) * 256;
#pragma unroll 1
    for (int kc = 0; kc < 4; ++kc) {
      int ci0 = kc * 64;
      __syncthreads();
#pragma unroll
      for (int i = 0; i < 4; ++i) {
        GLOAD16(xnp + baseA[i] + aoff + ci0, &As[(i * 32 + w * 8) * 64]);
        GLOAD16(wt + baseB + tap * 98304 + i * 8192 + ci0, &Bs[(i * 32 + w * 8) * 64]);
      }
      __syncthreads();
      bf16x8 af[4][2], bf[4][2];
#pragma unroll
      for (int mt = 0; mt < 4; ++mt)
#pragma unroll
        for (int k2 = 0; k2 < 2; ++k2) {
          af[mt][k2] = *(const bf16x8*)&As[(wr + mt * 16 + lr) * 64 + k2 * 32 + lg * 8];
          bf[mt][k2] = *(const bf16x8*)&Bs[(wc + mt * 16 + lr) * 64 + k2 * 32 + lg * 8];
        }
#pragma unroll
      for (int mt = 0; mt < 4; ++mt)
#pragma unroll
        for (int nt = 0; nt < 4; ++nt) {
          acc[mt][nt] = mfma16(af[mt][0], bf[nt][0], acc[mt][nt]);
          acc[mt][nt] = mfma16(af[mt][1], bf[nt][1], acc[mt][nt]);
        }
    }
  }
  float bias[4];
  int coBase = co0 + wc;
#pragma unroll
  for (int nt = 0; nt < 4; ++nt) bias[nt] = bias_in[coBase + nt * 16 + lr];
#pragma unroll
  for (int mt = 0; mt < 4; ++mt) {
    int p = p0 + wr + mt * 16 + lg * 4;
#pragma unroll
    for (int r = 0; r < 4; ++r) {
      size_t rowoff = ((size_t)(b * 4096 + p + r)) * 384;
#pragma unroll
      for (int nt = 0; nt < 4; ++nt) {
        int co = coBase + nt * 16 + lr;
        float v = acc[mt][nt][r] + bias[nt];
        if (co >= 256) v = fmaxf(v, 0.f);  // pre-ReLU the u channels
        y[rowoff + co] = f2bf(v);
      }
    }
  }
}

// ------------- depthwise 2x2 stride-2 convs, LDS-tiled -------------
__global__ __launch_bounds__(256) void k_kv(const unsigned short* __restrict__ y,
                                            const float* __restrict__ wkf, const float* __restrict__ bias_k,
                                            const float* __restrict__ wvf, const float* __restrict__ bias_v,
                                            unsigned short* __restrict__ kk, unsigned short* __restrict__ vv) {
  constexpr int LDW = 200;
  __shared__ unsigned short ty[128 * LDW];
  __shared__ unsigned short vt[128 * 33];
  int b = blockIdx.x >> 5, my = blockIdx.x & 31;
  int t = threadIdx.x;
  const unsigned short* ybase = y + ((size_t)(b * 4096 + my * 128)) * 384 + 64;
#pragma unroll
  for (int j = 0; j < 12; ++j) {
    int idx = j * 256 + t;
    int row = idx / 24, c8 = idx - row * 24;
    bf16x8 v = *(const bf16x8*)&ybase[(size_t)row * 384 + c8 * 8];
    *(bf16x8*)&ty[row * LDW + c8 * 8] = v;
  }
  __syncthreads();

  {
    int c = t & 63, wq = t >> 6;
    float wk0 = wkf[c * 4 + 0], wk1 = wkf[c * 4 + 1];
    float wk2 = wkf[c * 4 + 2], wk3 = wkf[c * 4 + 3];
    float bk = bias_k[c];
#pragma unroll
    for (int pass = 0; pass < 8; ++pass) {
      int mx = pass * 4 + wq;
      int r0 = 2 * mx, r1 = 2 * mx + 1;
      float a = bk;
      a += bf2f(ty[r0 * LDW + c]) * wk0;
      a += bf2f(ty[(r0 + 1) * LDW + c]) * wk1;
      a += bf2f(ty[(64 + r0) * LDW + c]) * wk2;
      a += bf2f(ty[(64 + r1) * LDW + c]) * wk3;
      kk[((size_t)(b * 1024 + my * 32 + mx)) * 64 + c] = f2bf(a);
    }
  }

  {
    int cv = t & 127, mxh = t >> 7;
    float wv0 = wvf[cv * 4 + 0], wv1 = wvf[cv * 4 + 1];
    float wv2 = wvf[cv * 4 + 2], wv3 = wvf[cv * 4 + 3];
    float bv = bias_v[cv];
    int col = 64 + cv;
#pragma unroll
    for (int pass = 0; pass < 16; ++pass) {
      int mx = pass * 2 + mxh;
      int r0 = 2 * mx, r1 = 2 * mx + 1;
      float a = bv;
      a += bf2f(ty[r0 * LDW + col]) * wv0;
      a += bf2f(ty[r1 * LDW + col]) * wv1;
      a += bf2f(ty[(64 + r0) * LDW + col]) * wv2;
      a += bf2f(ty[(64 + r1) * LDW + col]) * wv3;
      vt[cv * 33 + mx] = f2bf(a);
    }
  }
  __syncthreads();
  {
    int mx = t & 31, cvq = t >> 5;
#pragma unroll
    for (int i = 0; i < 16; ++i) {
      int cv = i * 8 + cvq;
      vv[((size_t)(b * 128 + cv)) * 1024 + my * 32 + mx] = vt[cv * 33 + mx];
    }
  }
}

// ---------------- flash attention (8 waves, 16 q/wave, K staged in LDS) ----------------
// writes relu(o) into y channels 128..255
__global__ __launch_bounds__(512, 4) void k_attn(unsigned short* __restrict__ y,
                                                 const unsigned short* __restrict__ kk,
                                                 const unsigned short* __restrict__ vvb) {
  __shared__ alignas(16) unsigned short Ks[2][4096];   // [64 key][64 ch], src-swizzled
  __shared__ alignas(16) unsigned short PT[8][64][16]; // per-wave [key][q]
  int blk = blockIdx.x;
  int b = blk >> 5, ntile = blk & 31;
  int t = threadIdx.x, w = t >> 6, l = t & 63;
  int lg = l >> 4, lr = l & 15;
  int nq0 = ntile * 128 + w * 16;
  const float SC = 0.125f * 1.44269504f;  // scale * log2(e)

  union { short8 s; bf16x8 b; } uo;
#pragma unroll
  for (int i = 0; i < 8; ++i) uo.s[i] = (short)0x3F80;  // bf16 1.0
  bf16x8 ones = uo.b;

  // Q fragment: 16 rows (queries), K=64
  bf16x8 qf[2];
#pragma unroll
  for (int c = 0; c < 2; ++c)
    qf[c] = *(const bf16x8*)&y[((size_t)(b * 4096 + nq0 + lr)) * 384 + c * 32 + lg * 8];

  f32x4 oa[8];
#pragma unroll
  for (int tt = 0; tt < 8; ++tt) oa[tt] = f32x4{0.f, 0.f, 0.f, 0.f};
  float mi[4], li[4];
#pragma unroll
  for (int r = 0; r < 4; ++r) { mi[r] = -1e30f; li[r] = 0.f; }

  // K staging: thread t covers key row t>>3, 16B chunk (t&7), source-side XOR swizzle
  int srow = t >> 3;
  int skg = (t & 7) ^ (srow & 7);
  const unsigned short* ksrc = kk + ((size_t)(b * 1024 + srow)) * 64 + skg * 8;
  unsigned short* ldst0 = &Ks[0][w * 512];
  unsigned short* ldst1 = &Ks[1][w * 512];

  GLOAD16(ksrc, ldst0);
  __syncthreads();

  for (int it = 0; it < 16; ++it) {
    int cur = it & 1;
    const unsigned short* Kc = &Ks[cur][0];
    if (it < 15) GLOAD16(ksrc + (it + 1) * 4096, cur ? ldst0 : ldst1);

    // ---- QK^T: s[mt][r] = S[q=lg*4+r][key=mt*16+lr] (raw) ----
    f32x4 s[4];
#pragma unroll
    for (int mt = 0; mt < 4; ++mt) {
      int row = mt * 16 + lr;
      int sw = (lr & 7) << 3;
      bf16x8 kf0 = *(const bf16x8*)&Kc[row * 64 + ((lg * 8) ^ sw)];
      bf16x8 kf1 = *(const bf16x8*)&Kc[row * 64 + ((32 + lg * 8) ^ sw)];
      f32x4 z = f32x4{0.f, 0.f, 0.f, 0.f};
      z = mfma16(qf[0], kf0, z);
      z = mfma16(qf[1], kf1, z);
      s[mt] = z;
    }

    // ---- online softmax (scaled into exp2 domain) ----
    float rm[4];
#pragma unroll
    for (int r = 0; r < 4; ++r)
      rm[r] = fmaxf(fmaxf(s[0][r], s[1][r]), fmaxf(s[2][r], s[3][r]));
#pragma unroll
    for (int msk = 1; msk <= 8; msk <<= 1)
#pragma unroll
      for (int r = 0; r < 4; ++r) rm[r] = fmaxf(rm[r], __shfl_xor(rm[r], msk));
    bool grow = false;
#pragma unroll
    for (int r = 0; r < 4; ++r) grow |= (rm[r] * SC > mi[r]);
    if (__any(grow)) {
#pragma unroll
      for (int r = 0; r < 4; ++r) {
        float nm = fmaxf(mi[r], rm[r] * SC);
        float corr = exp2f(mi[r] - nm);
        mi[r] = nm;
        li[r] *= corr;
#pragma unroll
        for (int tt = 0; tt < 8; ++tt) oa[tt][r] *= corr;
      }
    }
#pragma unroll
    for (int mt = 0; mt < 4; ++mt)
#pragma unroll
      for (int r = 0; r < 4; ++r)
        s[mt][r] = exp2f(fmaf(s[mt][r], SC, -mi[r]));

    // ---- P -> P_T[key][q] packed writes (4 queries contiguous per lane) ----
#pragma unroll
    for (int mt = 0; mt < 4; ++mt) {
      unsigned p01 = cvt_pk_bf16(s[mt][0], s[mt][1]);
      unsigned p23 = cvt_pk_bf16(s[mt][2], s[mt][3]);
      unsigned long long pk = ((unsigned long long)p23 << 32) | p01;
      *(unsigned long long*)&PT[w][mt * 16 + lr][lg * 4] = pk;
    }
    asm volatile("s_waitcnt lgkmcnt(0)" ::: "memory");

    // ---- transpose-read P as A-fragments: lane holds P[q=lr][key=kc*32+lg*8+j] ----
    bf16x8 pf[2];
#pragma unroll
    for (int kc = 0; kc < 2; ++kc) {
      unsigned base = (unsigned)(uintptr_t)&PT[w][kc * 32 + lg * 8][lr];
      unsigned r0x, r0y, r1x, r1y;
      uint2 t0, t1;
      asm volatile("ds_read_b64_tr_b16 %0, %1" : "=v"(t0) : "v"(base));
      asm volatile("ds_read_b64_tr_b16 %0, %1 offset:128" : "=v"(t1) : "v"(base));
      union { unsigned u[4]; bf16x8 b; } cv;
      cv.u[0] = t0.x; cv.u[1] = t0.y; cv.u[2] = t1.x; cv.u[3] = t1.y;
      pf[kc] = cv.b;
      (void)r0x; (void)r0y; (void)r1x; (void)r1y;
    }
    asm volatile("s_waitcnt lgkmcnt(0)" ::: "memory");
    __builtin_amdgcn_sched_barrier(0);

    // ---- row sums via MFMA against ones (consistent with bf16 P) ----
    {
      f32x4 zz = f32x4{0.f, 0.f, 0.f, 0.f};
      zz = mfma16(pf[0], ones, zz);
      zz = mfma16(pf[1], ones, zz);
#pragma unroll
      for (int r = 0; r < 4; ++r) li[r] += zz[r];
    }

    // ---- PV: oa[tt] += P x V ----
    size_t vbase = ((size_t)(b * 128)) * 1024 + it * 64 + lg * 8;
#pragma unroll
    for (int tt = 0; tt < 8; ++tt) {
      const unsigned short* vr = &vvb[vbase + (size_t)(tt * 16 + lr) * 1024];
      bf16x8 vf0 = *(const bf16x8*)&vr[0];
      bf16x8 vf1 = *(const bf16x8*)&vr[32];
      oa[tt] = mfma16(pf[0], vf0, oa[tt]);
      oa[tt] = mfma16(pf[1], vf1, oa[tt]);
    }
    __syncthreads();
  }

#pragma unroll
  for (int r = 0; r < 4; ++r) {
    float inv = 1.f / li[r];
    int p = nq0 + lg * 4 + r;
    size_t rowoff = ((size_t)(b * 4096 + p)) * 384 + 128;
#pragma unroll
    for (int tt = 0; tt < 8; ++tt) {
      float v = oa[tt][r] * inv;
      v = fmaxf(v, 0.f);  // pre-ReLU for conv1x1
      y[rowoff + tt * 16 + lr] = f2bf(v);
    }
  }
}

// ---------------- conv1x1 GEMM: out[b][co][p] f32 (NCHW) ----------------
__global__ __launch_bounds__(256) void k_conv1(const unsigned short* __restrict__ y,
                                               const unsigned short* __restrict__ wo2,
                                               const float* __restrict__ bias_out,
                                               float* __restrict__ out) {
  int ptile = blockIdx.x, cot = blockIdx.y, b = blockIdx.z;
  int p0 = ptile * 128, co0 = cot * 128;
  __shared__ alignas(16) unsigned short As[128 * 64];
  __shared__ alignas(16) unsigned short Bs[128 * 64];
  int t = threadIdx.x, w = t >> 6, l = t & 63;
  int rr = t >> 3, c8 = (t & 7) * 8;
  int lg = l >> 4, lr = l & 15;
  int baseA = (co0 + rr) * 256 + c8;
  size_t baseB = ((size_t)(b * 4096 + p0 + rr)) * 384 + 128 + c8;
  f32x4 acc[4][4];
#pragma unroll
  for (int i = 0; i < 4; ++i)
#pragma unroll
    for (int j = 0; j < 4; ++j) acc[i][j] = f32x4{0.f, 0.f, 0.f, 0.f};
  int wr = (w >> 1) * 64, wc = (w & 1) * 64;
#pragma unroll 1
  for (int kc = 0; kc < 4; ++kc) {
    int ci0 = kc * 64;
    __syncthreads();
#pragma unroll
    for (int i = 0; i < 4; ++i) {
      GLOAD16(wo2 + baseA + i * 8192 + ci0, &As[(i * 32 + w * 8) * 64]);
      GLOAD16(y + baseB + (size_t)i * 32 * 384 + ci0, &Bs[(i * 32 + w * 8) * 64]);
    }
    __syncthreads();
    bf16x8 af[4][2], bf[4][2];
#pragma unroll
    for (int mt = 0; mt < 4; ++mt)
#pragma unroll
      for (int k2 = 0; k2 < 2; ++k2) {
        af[mt][k2] = *(const bf16x8*)&As[(wr + mt * 16 + lr) * 64 + k2 * 32 + lg * 8];
        bf[mt][k2] = *(const bf16x8*)&Bs[(wc + mt * 16 + lr) * 64 + k2 * 32 + lg * 8];
      }
#pragma unroll
    for (int mt = 0; mt < 4; ++mt)
#pragma unroll
      for (int nt = 0; nt < 4; ++nt) {
        acc[mt][nt] = mfma16(af[mt][0], bf[nt][0], acc[mt][nt]);
        acc[mt][nt] = mfma16(af[mt][1], bf[nt][1], acc[mt][nt]);
      }
  }
#pragma unroll
  for (int mt = 0; mt < 4; ++mt)
#pragma unroll
    for (int r = 0; r < 4; ++r) {
      int co = co0 + wr + mt * 16 + lg * 4 + r;
      float bv = bias_out[co];
      size_t obase = ((size_t)(b * 256 + co)) << 12;
#pragma unroll
      for (int nt = 0; nt < 4; ++nt) {
        int p = p0 + wc + nt * 16 + lr;
        out[obase + p] = acc[mt][nt][r] + bv;
      }
    }
}

// ---------------- host launch ----------------
static constexpr size_t pad256(size_t x) { return (x + 255) & ~(size_t)255; }

extern "C" void kernel_launch(void* const* d_in, const int* in_sizes, int n_in,
                              void* d_out, int out_size, void* d_ws, size_t ws_size,
                              hipStream_t stream) {
  const float* x      = (const float*)d_in[0];
  const float* gn_g   = (const float*)d_in[1];
  const float* gn_b   = (const float*)d_in[2];
  const float* w_in   = (const float*)d_in[3];
  const float* bin_g  = (const float*)d_in[4];
  const float* bin_b  = (const float*)d_in[5];
  const float* bin_m  = (const float*)d_in[6];
  const float* bin_v  = (const float*)d_in[7];
  const float* w_k    = (const float*)d_in[8];
  const float* bk_g   = (const float*)d_in[9];
  const float* bk_b   = (const float*)d_in[10];
  const float* bk_m   = (const float*)d_in[11];
  const float* bk_v   = (const float*)d_in[12];
  const float* w_v    = (const float*)d_in[13];
  const float* bv_g   = (const float*)d_in[14];
  const float* bv_b   = (const float*)d_in[15];
  const float* bv_m   = (const float*)d_in[16];
  const float* bv_v   = (const float*)d_in[17];
  const float* w_out  = (const float*)d_in[18];
  const float* bo_g   = (const float*)d_in[19];
  const float* bo_b   = (const float*)d_in[20];
  const float* bo_m   = (const float*)d_in[21];
  const float* bo_v   = (const float*)d_in[22];
  float* out = (float*)d_out;

  char* ws = (char*)d_ws;
  size_t off = 0;
  float*          stats   = (float*)(ws + off);          off += pad256(128);
  unsigned short* wt      = (unsigned short*)(ws + off); off += pad256((size_t)9 * 384 * 256 * 2);
  float*          bias_in = (float*)(ws + off);          off += pad256(384 * 4);
  unsigned short* wo2     = (unsigned short*)(ws + off); off += pad256(256 * 256 * 2);
  float*          bias_out= (float*)(ws + off);          off += pad256(256 * 4);
  float*          wkf     = (float*)(ws + off);          off += pad256(64 * 4 * 4);
  float*          bias_k  = (float*)(ws + off);          off += pad256(64 * 4);
  float*          wvf     = (float*)(ws + off);          off += pad256(128 * 4 * 4);
  float*          bias_v  = (float*)(ws + off);          off += pad256(128 * 4);
  unsigned short* xnp     = (unsigned short*)(ws + off); off += pad256((size_t)16 * 66 * 66 * 256 * 2);
  unsigned short* y       = (unsigned short*)(ws + off); off += pad256((size_t)16 * 4096 * 384 * 2);
  unsigned short* kk      = (unsigned short*)(ws + off); off += pad256((size_t)16 * 1024 * 64 * 2);
  unsigned short* vv      = (unsigned short*)(ws + off); off += pad256((size_t)16 * 128 * 1024 * 2);
  (void)ws_size; (void)out_size; (void)n_in; (void)in_sizes;

  hipMemsetAsync(stats, 0, 256, stream);
  hipMemsetAsync(xnp, 0, (size_t)16 * 66 * 66 * 256 * 2, stream);

  k_gn_stats<<<1024, 256, 0, stream>>>(x, stats);
  k_prep_wt<<<3456, 256, 0, stream>>>(w_in, bin_g, bin_v, wt);
  k_prep_misc<<<260, 256, 0, stream>>>(w_out, bo_g, bo_b, bo_m, bo_v,
                                       bin_g, bin_b, bin_m, bin_v,
                                       w_k, bk_g, bk_b, bk_m, bk_v,
                                       w_v, bv_g, bv_b, bv_m, bv_v,
                                       wo2, bias_in, bias_out, wkf, bias_k, wvf, bias_v);
  k_gn_norm<<<dim3(64, 4, 16), 256, 0, stream>>>(x, stats, gn_g, gn_b, xnp);
  k_conv3<<<dim3(32, 3, 16), 256, 0, stream>>>(xnp, wt, bias_in, y);
  k_kv<<<512, 256, 0, stream>>>(y, wkf, bias_k, wvf, bias_v, kk, vv);
  k_attn<<<512, 512, 0, stream>>>(y, kk, vv);
  k_conv1<<<dim3(32, 2, 16), 256, 0, stream>>>(y, wo2, bias_out, out);
}

// Round 5
// 454.090 us; speedup vs baseline: 1.1345x; 1.0331x over previous
//
#include <hip/hip_runtime.h>
#include <stdint.h>

#define EPSV 1e-5f

typedef __attribute__((ext_vector_type(8))) short short8;
typedef __attribute__((ext_vector_type(4))) float f32x4;
typedef __bf16 bf16x8 __attribute__((ext_vector_type(8)));

__device__ __forceinline__ unsigned short f2bf(float f) {
  union { float f; unsigned int u; } v; v.f = f;
  unsigned int r = (v.u + 0x7FFFu + ((v.u >> 16) & 1u)) >> 16;
  return (unsigned short)r;
}
__device__ __forceinline__ float bf2f(unsigned short h) {
  union { unsigned int u; float f; } v; v.u = ((unsigned int)h) << 16;
  return v.f;
}

__device__ __forceinline__ f32x4 mfma16(bf16x8 a, bf16x8 b, f32x4 c) {
  return __builtin_amdgcn_mfma_f32_16x16x32_bf16(a, b, c, 0, 0, 0);
}

__device__ __forceinline__ unsigned cvt_pk_bf16(float lo, float hi) {
  unsigned r;
  asm("v_cvt_pk_bf16_f32 %0, %1, %2" : "=v"(r) : "v"(lo), "v"(hi));
  return r;
}

__device__ __forceinline__ bf16x8 dsread16(const unsigned short* p) {
  unsigned off = (unsigned)(uintptr_t)(const __attribute__((address_space(3))) unsigned short*)p;
  bf16x8 r;
  asm volatile("ds_read_b128 %0, %1" : "=v"(r) : "v"(off));
  return r;
}

#define GLOAD16(g, l)                                                          \
  __builtin_amdgcn_global_load_lds(                                            \
      (const __attribute__((address_space(1))) void*)(g),                      \
      (__attribute__((address_space(3))) void*)(l), 16, 0, 0)

// ---------------- GroupNorm stats: per-sample sum / sumsq ----------------
__global__ __launch_bounds__(256) void k_gn_stats(const float* __restrict__ x,
                                                  float* __restrict__ stats) {
  int b = blockIdx.x >> 6, chunk = blockIdx.x & 63;
  const float4* xp = (const float4*)(x + ((size_t)b << 20) + (size_t)chunk * 16384);
  int t = threadIdx.x;
  float s = 0.f, q = 0.f;
#pragma unroll
  for (int i = 0; i < 16; ++i) {
    float4 v = xp[i * 256 + t];
    s += v.x + v.y + v.z + v.w;
    q += v.x * v.x + v.y * v.y + v.z * v.z + v.w * v.w;
  }
#pragma unroll
  for (int m = 1; m <= 32; m <<= 1) { s += __shfl_xor(s, m); q += __shfl_xor(q, m); }
  __shared__ float ls[8];
  int w = t >> 6, l = t & 63;
  if (l == 0) { ls[w * 2] = s; ls[w * 2 + 1] = q; }
  __syncthreads();
  if (t == 0) {
    float S = ls[0] + ls[2] + ls[4] + ls[6];
    float Q = ls[1] + ls[3] + ls[5] + ls[7];
    atomicAdd(&stats[b * 2], S);
    atomicAdd(&stats[b * 2 + 1], Q);
  }
}

// ---------- normalize + NCHW->padded-NHWC transpose (bf16) ----------
__global__ __launch_bounds__(256) void k_gn_norm(const float* __restrict__ x,
                                                 const float* __restrict__ stats,
                                                 const float* __restrict__ g,
                                                 const float* __restrict__ bb,
                                                 unsigned short* __restrict__ xnp) {
  __shared__ float tile[64][65];
  int pt = blockIdx.x;  // image row y (64 pixels)
  int ct = blockIdx.y;  // ci tile (4)
  int b = blockIdx.z;
  int t = threadIdx.x, tr = t >> 6, tc = t & 63;
  const float* xb = x + ((size_t)b << 20) + (size_t)(ct * 64) * 4096 + pt * 64;
#pragma unroll
  for (int i = 0; i < 16; ++i) {
    int r = i * 4 + tr;
    tile[r][tc] = xb[(size_t)r * 4096 + tc];
  }
  __syncthreads();
  float mu = stats[b * 2] * (1.f / 1048576.f);
  float var = stats[b * 2 + 1] * (1.f / 1048576.f) - mu * mu;
  float istd = rsqrtf(var + EPSV);
  float gg = g[ct * 64 + tc] * istd;
  float bv = bb[ct * 64 + tc];
  unsigned short* out = xnp + (((size_t)b * 66 + (pt + 1)) * 66 + 1) * 256 + ct * 64 + tc;
#pragma unroll
  for (int i = 0; i < 16; ++i) {
    int pcol = i * 4 + tr;
    float v = (tile[tc][pcol] - mu) * gg + bv;
    out[(size_t)pcol * 256] = f2bf(v);
  }
}

// ------------- weight prep: w_in -> wt[tap][co][ci] bf16, BN folded -------------
__global__ __launch_bounds__(256) void k_prep_wt(const float* __restrict__ w_in,
                                                 const float* __restrict__ bg,
                                                 const float* __restrict__ bv,
                                                 unsigned short* __restrict__ wt) {
  int idx = blockIdx.x * 256 + threadIdx.x;
  if (idx >= 9 * 384 * 256) return;
  int tap = idx / 98304;
  int rem = idx - tap * 98304;
  int co = rem >> 8, ci = rem & 255;
  float s = bg[co] * rsqrtf(bv[co] + EPSV);
  wt[idx] = f2bf(w_in[(size_t)(co * 256 + ci) * 9 + tap] * s);
}

__global__ __launch_bounds__(256) void k_prep_misc(
    const float* w_out, const float* og, const float* ob, const float* om, const float* ov,
    const float* big, const float* bib, const float* bim, const float* biv,
    const float* w_k, const float* kg, const float* kb, const float* km, const float* kvv,
    const float* w_v, const float* vg, const float* vb, const float* vm, const float* vvv,
    unsigned short* wo2, float* bias_in, float* bias_out,
    float* wkf, float* bias_k, float* wvf, float* bias_v) {
  int idx = blockIdx.x * 256 + threadIdx.x;
  if (idx < 65536) {
    int co = idx >> 8;
    float s = og[co] * rsqrtf(ov[co] + EPSV);
    wo2[idx] = f2bf(w_out[idx] * s);
    return;
  }
  idx -= 65536;
  if (idx < 384) {
    float s = big[idx] * rsqrtf(biv[idx] + EPSV);
    bias_in[idx] = bib[idx] - bim[idx] * s;
    return;
  }
  idx -= 384;
  if (idx < 256) {
    float s = og[idx] * rsqrtf(ov[idx] + EPSV);
    bias_out[idx] = ob[idx] - om[idx] * s;
    return;
  }
  idx -= 256;
  if (idx < 64) {
    float s = kg[idx] * rsqrtf(kvv[idx] + EPSV);
#pragma unroll
    for (int tp = 0; tp < 4; ++tp) wkf[idx * 4 + tp] = w_k[idx * 4 + tp] * s;
    bias_k[idx] = kb[idx] - km[idx] * s;
    return;
  }
  idx -= 64;
  if (idx < 128) {
    float s = vg[idx] * rsqrtf(vvv[idx] + EPSV);
#pragma unroll
    for (int tp = 0; tp < 4; ++tp) wvf[idx * 4 + tp] = w_v[idx * 4 + tp] * s;
    bias_v[idx] = vb[idx] - vm[idx] * s;
    return;
  }
}

// ---------------- conv3x3 implicit GEMM, pipelined 256x192 tile ----------------
// y[b][p][co] bf16. Per block: BM=256 pixels, BN=192 co, BK=64, 8 waves (2Mx4N),
// per-wave 128x48. Counted vmcnt(7) prefetch 1 K-step ahead; LDS chunk^=(row&7)
// XOR swizzle (source-side pre-swizzle for global_load_lds, swizzled ds_read).
__global__ __launch_bounds__(512, 2) void k_conv3(const unsigned short* __restrict__ xnp,
                                                  const unsigned short* __restrict__ wt,
                                                  const float* __restrict__ bias_in,
                                                  unsigned short* __restrict__ y) {
  __shared__ alignas(16) unsigned short As[2][256 * 64];
  __shared__ alignas(16) unsigned short Bs[2][192 * 64];
  int pt = blockIdx.x, cot = blockIdx.y, b = blockIdx.z;
  int p0 = pt * 256, co0 = cot * 192;
  int t = threadIdx.x, w = t >> 6, l = t & 63;
  int lg = l >> 4, lr = l & 15;
  int wrM = (w >> 2) * 128, wrN = (w & 3) * 48;

  // staging: thread covers 16B slot (i*512+t); row=slot>>3, physical chunk=t&7,
  // logical chunk = (t&7) ^ (row&7)  (row&7 == (t>>3)&7 since 512%8==0... i*512%8==0)
  int lchunk = (t & 7) ^ ((t >> 3) & 7);
  int abase[4];
#pragma unroll
  for (int i = 0; i < 4; ++i) {
    int row = (i * 512 + t) >> 3;
    int p = p0 + row;
    int yy = p >> 6, xx = p & 63;
    abase[i] = ((b * 66 + yy) * 66 + xx) * 256 + lchunk * 8;
  }
  int bbase[3];
#pragma unroll
  for (int i = 0; i < 3; ++i) {
    int row = (i * 512 + t) >> 3;
    bbase[i] = (co0 + row) * 256 + lchunk * 8;
  }

  f32x4 acc[8][3];
#pragma unroll
  for (int i = 0; i < 8; ++i)
#pragma unroll
    for (int j = 0; j < 3; ++j) acc[i][j] = f32x4{0.f, 0.f, 0.f, 0.f};

#define STAGE(step, buf)                                                       \
  do {                                                                         \
    int tap_ = (step) >> 2, kc_ = (step) & 3;                                  \
    int dy_ = (tap_ * 11) >> 5;                                                \
    int dx_ = tap_ - dy_ * 3;                                                  \
    int aoff_ = (dy_ * 66 + dx_) * 256 + kc_ * 64;                             \
    int boff_ = tap_ * 98304 + kc_ * 64;                                       \
    _Pragma("unroll")                                                          \
    for (int i_ = 0; i_ < 4; ++i_)                                             \
      GLOAD16(xnp + abase[i_] + aoff_, &As[buf][(i_ * 512 + w * 64) * 8]);     \
    _Pragma("unroll")                                                          \
    for (int i_ = 0; i_ < 3; ++i_)                                             \
      GLOAD16(wt + bbase[i_] + boff_, &Bs[buf][(i_ * 512 + w * 64) * 8]);      \
  } while (0)

  STAGE(0, 0);

  for (int step = 0; step < 36; ++step) {
    int cur = step & 1;
    asm volatile("" ::: "memory");  // pin STAGE below the previous barrier
    if (step < 35) {
      STAGE(step + 1, cur ^ 1);
      asm volatile("s_waitcnt vmcnt(7)" ::: "memory");
    } else {
      asm volatile("s_waitcnt vmcnt(0)" ::: "memory");
    }
    __builtin_amdgcn_s_barrier();
    __builtin_amdgcn_sched_barrier(0);

    const unsigned short* Ac = As[cur];
    const unsigned short* Bc = Bs[cur];

    bf16x8 bfr[2][3];
#pragma unroll
    for (int k2 = 0; k2 < 2; ++k2)
#pragma unroll
      for (int nt = 0; nt < 3; ++nt) {
        int row = wrN + nt * 16 + lr;
        bfr[k2][nt] = dsread16(&Bc[row * 64 + (((k2 * 4 + lg) ^ (row & 7)) * 8)]);
      }
#pragma unroll
    for (int mh = 0; mh < 2; ++mh) {
      bf16x8 afr[4][2];
#pragma unroll
      for (int mt = 0; mt < 4; ++mt)
#pragma unroll
        for (int k2 = 0; k2 < 2; ++k2) {
          int row = wrM + mh * 64 + mt * 16 + lr;
          afr[mt][k2] = dsread16(&Ac[row * 64 + (((k2 * 4 + lg) ^ (row & 7)) * 8)]);
        }
      asm volatile("s_waitcnt lgkmcnt(0)" ::: "memory");
      __builtin_amdgcn_sched_barrier(0);
      __builtin_amdgcn_s_setprio(1);
#pragma unroll
      for (int mt = 0; mt < 4; ++mt)
#pragma unroll
        for (int nt = 0; nt < 3; ++nt) {
          acc[mh * 4 + mt][nt] = mfma16(afr[mt][0], bfr[0][nt], acc[mh * 4 + mt][nt]);
          acc[mh * 4 + mt][nt] = mfma16(afr[mt][1], bfr[1][nt], acc[mh * 4 + mt][nt]);
        }
      __builtin_amdgcn_s_setprio(0);
    }
    __builtin_amdgcn_sched_barrier(0);
    __builtin_amdgcn_s_barrier();
  }
#undef STAGE

  float bias[3];
#pragma unroll
  for (int nt = 0; nt < 3; ++nt) bias[nt] = bias_in[co0 + wrN + nt * 16 + lr];
#pragma unroll
  for (int m8 = 0; m8 < 8; ++m8) {
#pragma unroll
    for (int r = 0; r < 4; ++r) {
      int p = p0 + wrM + m8 * 16 + lg * 4 + r;
      size_t rowoff = ((size_t)(b * 4096 + p)) * 384;
#pragma unroll
      for (int nt = 0; nt < 3; ++nt) {
        int co = co0 + wrN + nt * 16 + lr;
        float v = acc[m8][nt][r] + bias[nt];
        if (co >= 256) v = fmaxf(v, 0.f);  // pre-ReLU the u channels
        y[rowoff + co] = f2bf(v);
      }
    }
  }
}

// ------------- depthwise 2x2 stride-2 convs, LDS-tiled -------------
__global__ __launch_bounds__(256) void k_kv(const unsigned short* __restrict__ y,
                                            const float* __restrict__ wkf, const float* __restrict__ bias_k,
                                            const float* __restrict__ wvf, const float* __restrict__ bias_v,
                                            unsigned short* __restrict__ kk, unsigned short* __restrict__ vv) {
  constexpr int LDW = 200;
  __shared__ unsigned short ty[128 * LDW];
  __shared__ unsigned short vt[128 * 33];
  int b = blockIdx.x >> 5, my = blockIdx.x & 31;
  int t = threadIdx.x;
  const unsigned short* ybase = y + ((size_t)(b * 4096 + my * 128)) * 384 + 64;
#pragma unroll
  for (int j = 0; j < 12; ++j) {
    int idx = j * 256 + t;
    int row = idx / 24, c8 = idx - row * 24;
    bf16x8 v = *(const bf16x8*)&ybase[(size_t)row * 384 + c8 * 8];
    *(bf16x8*)&ty[row * LDW + c8 * 8] = v;
  }
  __syncthreads();

  {
    int c = t & 63, wq = t >> 6;
    float wk0 = wkf[c * 4 + 0], wk1 = wkf[c * 4 + 1];
    float wk2 = wkf[c * 4 + 2], wk3 = wkf[c * 4 + 3];
    float bk = bias_k[c];
#pragma unroll
    for (int pass = 0; pass < 8; ++pass) {
      int mx = pass * 4 + wq;
      int r0 = 2 * mx, r1 = 2 * mx + 1;
      float a = bk;
      a += bf2f(ty[r0 * LDW + c]) * wk0;
      a += bf2f(ty[(r0 + 1) * LDW + c]) * wk1;
      a += bf2f(ty[(64 + r0) * LDW + c]) * wk2;
      a += bf2f(ty[(64 + r1) * LDW + c]) * wk3;
      kk[((size_t)(b * 1024 + my * 32 + mx)) * 64 + c] = f2bf(a);
    }
  }

  {
    int cv = t & 127, mxh = t >> 7;
    float wv0 = wvf[cv * 4 + 0], wv1 = wvf[cv * 4 + 1];
    float wv2 = wvf[cv * 4 + 2], wv3 = wvf[cv * 4 + 3];
    float bv = bias_v[cv];
    int col = 64 + cv;
#pragma unroll
    for (int pass = 0; pass < 16; ++pass) {
      int mx = pass * 2 + mxh;
      int r0 = 2 * mx, r1 = 2 * mx + 1;
      float a = bv;
      a += bf2f(ty[r0 * LDW + col]) * wv0;
      a += bf2f(ty[r1 * LDW + col]) * wv1;
      a += bf2f(ty[(64 + r0) * LDW + col]) * wv2;
      a += bf2f(ty[(64 + r1) * LDW + col]) * wv3;
      vt[cv * 33 + mx] = f2bf(a);
    }
  }
  __syncthreads();
  {
    int mx = t & 31, cvq = t >> 5;
#pragma unroll
    for (int i = 0; i < 16; ++i) {
      int cv = i * 8 + cvq;
      vv[((size_t)(b * 128 + cv)) * 1024 + my * 32 + mx] = vt[cv * 33 + mx];
    }
  }
}

// ---------------- flash attention (8 waves, 16 q/wave, K staged in LDS) ----------------
// writes relu(o) into y channels 128..255
__global__ __launch_bounds__(512, 4) void k_attn(unsigned short* __restrict__ y,
                                                 const unsigned short* __restrict__ kk,
                                                 const unsigned short* __restrict__ vvb) {
  __shared__ alignas(16) unsigned short Ks[2][4096];   // [64 key][64 ch], src-swizzled
  __shared__ alignas(16) unsigned short PT[8][64][16]; // per-wave [key][q]
  int blk = blockIdx.x;
  int b = blk >> 5, ntile = blk & 31;
  int t = threadIdx.x, w = t >> 6, l = t & 63;
  int lg = l >> 4, lr = l & 15;
  int nq0 = ntile * 128 + w * 16;
  const float SC = 0.125f * 1.44269504f;  // scale * log2(e)

  union { short8 s; bf16x8 b; } uo;
#pragma unroll
  for (int i = 0; i < 8; ++i) uo.s[i] = (short)0x3F80;  // bf16 1.0
  bf16x8 ones = uo.b;

  // Q fragment: 16 rows (queries), K=64
  bf16x8 qf[2];
#pragma unroll
  for (int c = 0; c < 2; ++c)
    qf[c] = *(const bf16x8*)&y[((size_t)(b * 4096 + nq0 + lr)) * 384 + c * 32 + lg * 8];

  f32x4 oa[8];
#pragma unroll
  for (int tt = 0; tt < 8; ++tt) oa[tt] = f32x4{0.f, 0.f, 0.f, 0.f};
  float mi[4], li[4];
#pragma unroll
  for (int r = 0; r < 4; ++r) { mi[r] = -1e30f; li[r] = 0.f; }

  // K staging: thread t covers key row t>>3, 16B chunk (t&7), source-side XOR swizzle
  int srow = t >> 3;
  int skg = (t & 7) ^ (srow & 7);
  const unsigned short* ksrc = kk + ((size_t)(b * 1024 + srow)) * 64 + skg * 8;
  unsigned short* ldst0 = &Ks[0][w * 512];
  unsigned short* ldst1 = &Ks[1][w * 512];

  GLOAD16(ksrc, ldst0);
  __syncthreads();

  for (int it = 0; it < 16; ++it) {
    int cur = it & 1;
    const unsigned short* Kc = &Ks[cur][0];
    if (it < 15) GLOAD16(ksrc + (it + 1) * 4096, cur ? ldst0 : ldst1);

    // ---- QK^T: s[mt][r] = S[q=lg*4+r][key=mt*16+lr] (raw) ----
    f32x4 s[4];
#pragma unroll
    for (int mt = 0; mt < 4; ++mt) {
      int row = mt * 16 + lr;
      int sw = (lr & 7) << 3;
      bf16x8 kf0 = *(const bf16x8*)&Kc[row * 64 + ((lg * 8) ^ sw)];
      bf16x8 kf1 = *(const bf16x8*)&Kc[row * 64 + ((32 + lg * 8) ^ sw)];
      f32x4 z = f32x4{0.f, 0.f, 0.f, 0.f};
      z = mfma16(qf[0], kf0, z);
      z = mfma16(qf[1], kf1, z);
      s[mt] = z;
    }

    // ---- online softmax (scaled into exp2 domain) ----
    float rm[4];
#pragma unroll
    for (int r = 0; r < 4; ++r)
      rm[r] = fmaxf(fmaxf(s[0][r], s[1][r]), fmaxf(s[2][r], s[3][r]));
#pragma unroll
    for (int msk = 1; msk <= 8; msk <<= 1)
#pragma unroll
      for (int r = 0; r < 4; ++r) rm[r] = fmaxf(rm[r], __shfl_xor(rm[r], msk));
    bool grow = false;
#pragma unroll
    for (int r = 0; r < 4; ++r) grow |= (rm[r] * SC > mi[r]);
    if (__any(grow)) {
#pragma unroll
      for (int r = 0; r < 4; ++r) {
        float nm = fmaxf(mi[r], rm[r] * SC);
        float corr = exp2f(mi[r] - nm);
        mi[r] = nm;
        li[r] *= corr;
#pragma unroll
        for (int tt = 0; tt < 8; ++tt) oa[tt][r] *= corr;
      }
    }
#pragma unroll
    for (int mt = 0; mt < 4; ++mt)
#pragma unroll
      for (int r = 0; r < 4; ++r)
        s[mt][r] = exp2f(fmaf(s[mt][r], SC, -mi[r]));

    // ---- P -> P_T[key][q] packed writes (4 queries contiguous per lane) ----
#pragma unroll
    for (int mt = 0; mt < 4; ++mt) {
      unsigned p01 = cvt_pk_bf16(s[mt][0], s[mt][1]);
      unsigned p23 = cvt_pk_bf16(s[mt][2], s[mt][3]);
      unsigned long long pk = ((unsigned long long)p23 << 32) | p01;
      *(unsigned long long*)&PT[w][mt * 16 + lr][lg * 4] = pk;
    }
    asm volatile("s_waitcnt lgkmcnt(0)" ::: "memory");

    // ---- transpose-read P as A-fragments: lane holds P[q=lr][key=kc*32+lg*8+j] ----
    bf16x8 pf[2];
#pragma unroll
    for (int kc = 0; kc < 2; ++kc) {
      unsigned base = (unsigned)(uintptr_t)&PT[w][kc * 32 + lg * 8][lr];
      uint2 t0, t1;
      asm volatile("ds_read_b64_tr_b16 %0, %1" : "=v"(t0) : "v"(base));
      asm volatile("ds_read_b64_tr_b16 %0, %1 offset:128" : "=v"(t1) : "v"(base));
      union { unsigned u[4]; bf16x8 b; } cv;
      cv.u[0] = t0.x; cv.u[1] = t0.y; cv.u[2] = t1.x; cv.u[3] = t1.y;
      pf[kc] = cv.b;
    }
    asm volatile("s_waitcnt lgkmcnt(0)" ::: "memory");
    __builtin_amdgcn_sched_barrier(0);

    // ---- row sums via MFMA against ones (consistent with bf16 P) ----
    {
      f32x4 zz = f32x4{0.f, 0.f, 0.f, 0.f};
      zz = mfma16(pf[0], ones, zz);
      zz = mfma16(pf[1], ones, zz);
#pragma unroll
      for (int r = 0; r < 4; ++r) li[r] += zz[r];
    }

    // ---- PV: oa[tt] += P x V ----
    size_t vbase = ((size_t)(b * 128)) * 1024 + it * 64 + lg * 8;
#pragma unroll
    for (int tt = 0; tt < 8; ++tt) {
      const unsigned short* vr = &vvb[vbase + (size_t)(tt * 16 + lr) * 1024];
      bf16x8 vf0 = *(const bf16x8*)&vr[0];
      bf16x8 vf1 = *(const bf16x8*)&vr[32];
      oa[tt] = mfma16(pf[0], vf0, oa[tt]);
      oa[tt] = mfma16(pf[1], vf1, oa[tt]);
    }
    __syncthreads();
  }

#pragma unroll
  for (int r = 0; r < 4; ++r) {
    float inv = 1.f / li[r];
    int p = nq0 + lg * 4 + r;
    size_t rowoff = ((size_t)(b * 4096 + p)) * 384 + 128;
#pragma unroll
    for (int tt = 0; tt < 8; ++tt) {
      float v = oa[tt][r] * inv;
      v = fmaxf(v, 0.f);  // pre-ReLU for conv1x1
      y[rowoff + tt * 16 + lr] = f2bf(v);
    }
  }
}

// ---------------- conv1x1 GEMM: out[b][co][p] f32 (NCHW) ----------------
__global__ __launch_bounds__(256) void k_conv1(const unsigned short* __restrict__ y,
                                               const unsigned short* __restrict__ wo2,
                                               const float* __restrict__ bias_out,
                                               float* __restrict__ out) {
  int ptile = blockIdx.x, cot = blockIdx.y, b = blockIdx.z;
  int p0 = ptile * 128, co0 = cot * 128;
  __shared__ alignas(16) unsigned short As[128 * 64];
  __shared__ alignas(16) unsigned short Bs[128 * 64];
  int t = threadIdx.x, w = t >> 6, l = t & 63;
  int rr = t >> 3, c8 = (t & 7) * 8;
  int lg = l >> 4, lr = l & 15;
  int baseA = (co0 + rr) * 256 + c8;
  size_t baseB = ((size_t)(b * 4096 + p0 + rr)) * 384 + 128 + c8;
  f32x4 acc[4][4];
#pragma unroll
  for (int i = 0; i < 4; ++i)
#pragma unroll
    for (int j = 0; j < 4; ++j) acc[i][j] = f32x4{0.f, 0.f, 0.f, 0.f};
  int wr = (w >> 1) * 64, wc = (w & 1) * 64;
#pragma unroll 1
  for (int kc = 0; kc < 4; ++kc) {
    int ci0 = kc * 64;
    __syncthreads();
#pragma unroll
    for (int i = 0; i < 4; ++i) {
      GLOAD16(wo2 + baseA + i * 8192 + ci0, &As[(i * 32 + w * 8) * 64]);
      GLOAD16(y + baseB + (size_t)i * 32 * 384 + ci0, &Bs[(i * 32 + w * 8) * 64]);
    }
    __syncthreads();
    bf16x8 af[4][2], bf[4][2];
#pragma unroll
    for (int mt = 0; mt < 4; ++mt)
#pragma unroll
      for (int k2 = 0; k2 < 2; ++k2) {
        af[mt][k2] = *(const bf16x8*)&As[(wr + mt * 16 + lr) * 64 + k2 * 32 + lg * 8];
        bf[mt][k2] = *(const bf16x8*)&Bs[(wc + mt * 16 + lr) * 64 + k2 * 32 + lg * 8];
      }
#pragma unroll
    for (int mt = 0; mt < 4; ++mt)
#pragma unroll
      for (int nt = 0; nt < 4; ++nt) {
        acc[mt][nt] = mfma16(af[mt][0], bf[nt][0], acc[mt][nt]);
        acc[mt][nt] = mfma16(af[mt][1], bf[nt][1], acc[mt][nt]);
      }
  }
#pragma unroll
  for (int mt = 0; mt < 4; ++mt)
#pragma unroll
    for (int r = 0; r < 4; ++r) {
      int co = co0 + wr + mt * 16 + lg * 4 + r;
      float bv = bias_out[co];
      size_t obase = ((size_t)(b * 256 + co)) << 12;
#pragma unroll
      for (int nt = 0; nt < 4; ++nt) {
        int p = p0 + wc + nt * 16 + lr;
        out[obase + p] = acc[mt][nt][r] + bv;
      }
    }
}

// ---------------- host launch ----------------
static constexpr size_t pad256(size_t x) { return (x + 255) & ~(size_t)255; }

extern "C" void kernel_launch(void* const* d_in, const int* in_sizes, int n_in,
                              void* d_out, int out_size, void* d_ws, size_t ws_size,
                              hipStream_t stream) {
  const float* x      = (const float*)d_in[0];
  const float* gn_g   = (const float*)d_in[1];
  const float* gn_b   = (const float*)d_in[2];
  const float* w_in   = (const float*)d_in[3];
  const float* bin_g  = (const float*)d_in[4];
  const float* bin_b  = (const float*)d_in[5];
  const float* bin_m  = (const float*)d_in[6];
  const float* bin_v  = (const float*)d_in[7];
  const float* w_k    = (const float*)d_in[8];
  const float* bk_g   = (const float*)d_in[9];
  const float* bk_b   = (const float*)d_in[10];
  const float* bk_m   = (const float*)d_in[11];
  const float* bk_v   = (const float*)d_in[12];
  const float* w_v    = (const float*)d_in[13];
  const float* bv_g   = (const float*)d_in[14];
  const float* bv_b   = (const float*)d_in[15];
  const float* bv_m   = (const float*)d_in[16];
  const float* bv_v   = (const float*)d_in[17];
  const float* w_out  = (const float*)d_in[18];
  const float* bo_g   = (const float*)d_in[19];
  const float* bo_b   = (const float*)d_in[20];
  const float* bo_m   = (const float*)d_in[21];
  const float* bo_v   = (const float*)d_in[22];
  float* out = (float*)d_out;

  char* ws = (char*)d_ws;
  size_t off = 0;
  float*          stats   = (float*)(ws + off);          off += pad256(128);
  unsigned short* wt      = (unsigned short*)(ws + off); off += pad256((size_t)9 * 384 * 256 * 2);
  float*          bias_in = (float*)(ws + off);          off += pad256(384 * 4);
  unsigned short* wo2     = (unsigned short*)(ws + off); off += pad256(256 * 256 * 2);
  float*          bias_out= (float*)(ws + off);          off += pad256(256 * 4);
  float*          wkf     = (float*)(ws + off);          off += pad256(64 * 4 * 4);
  float*          bias_k  = (float*)(ws + off);          off += pad256(64 * 4);
  float*          wvf     = (float*)(ws + off);          off += pad256(128 * 4 * 4);
  float*          bias_v  = (float*)(ws + off);          off += pad256(128 * 4);
  unsigned short* xnp     = (unsigned short*)(ws + off); off += pad256((size_t)16 * 66 * 66 * 256 * 2);
  unsigned short* y       = (unsigned short*)(ws + off); off += pad256((size_t)16 * 4096 * 384 * 2);
  unsigned short* kk      = (unsigned short*)(ws + off); off += pad256((size_t)16 * 1024 * 64 * 2);
  unsigned short* vv      = (unsigned short*)(ws + off); off += pad256((size_t)16 * 128 * 1024 * 2);
  (void)ws_size; (void)out_size; (void)n_in; (void)in_sizes;

  hipMemsetAsync(stats, 0, 256, stream);
  hipMemsetAsync(xnp, 0, (size_t)16 * 66 * 66 * 256 * 2, stream);

  k_gn_stats<<<1024, 256, 0, stream>>>(x, stats);
  k_prep_wt<<<3456, 256, 0, stream>>>(w_in, bin_g, bin_v, wt);
  k_prep_misc<<<260, 256, 0, stream>>>(w_out, bo_g, bo_b, bo_m, bo_v,
                                       bin_g, bin_b, bin_m, bin_v,
                                       w_k, bk_g, bk_b, bk_m, bk_v,
                                       w_v, bv_g, bv_b, bv_m, bv_v,
                                       wo2, bias_in, bias_out, wkf, bias_k, wvf, bias_v);
  k_gn_norm<<<dim3(64, 4, 16), 256, 0, stream>>>(x, stats, gn_g, gn_b, xnp);
  k_conv3<<<dim3(16, 2, 16), 512, 0, stream>>>(xnp, wt, bias_in, y);
  k_kv<<<512, 256, 0, stream>>>(y, wkf, bias_k, wvf, bias_v, kk, vv);
  k_attn<<<512, 512, 0, stream>>>(y, kk, vv);
  k_conv1<<<dim3(32, 2, 16), 256, 0, stream>>>(y, wo2, bias_out, out);
}

// Round 6
// 438.430 us; speedup vs baseline: 1.1750x; 1.0357x over previous
//
#include <hip/hip_runtime.h>
#include <stdint.h>

#define EPSV 1e-5f

typedef __attribute__((ext_vector_type(8))) short short8;
typedef __attribute__((ext_vector_type(4))) float f32x4;
typedef __bf16 bf16x8 __attribute__((ext_vector_type(8)));

__device__ __forceinline__ unsigned short f2bf(float f) {
  union { float f; unsigned int u; } v; v.f = f;
  unsigned int r = (v.u + 0x7FFFu + ((v.u >> 16) & 1u)) >> 16;
  return (unsigned short)r;
}
__device__ __forceinline__ float bf2f(unsigned short h) {
  union { unsigned int u; float f; } v; v.u = ((unsigned int)h) << 16;
  return v.f;
}

__device__ __forceinline__ f32x4 mfma16(bf16x8 a, bf16x8 b, f32x4 c) {
  return __builtin_amdgcn_mfma_f32_16x16x32_bf16(a, b, c, 0, 0, 0);
}

__device__ __forceinline__ unsigned cvt_pk_bf16(float lo, float hi) {
  unsigned r;
  asm("v_cvt_pk_bf16_f32 %0, %1, %2" : "=v"(r) : "v"(lo), "v"(hi));
  return r;
}

__device__ __forceinline__ bf16x8 dsread16(const unsigned short* p) {
  unsigned off = (unsigned)(uintptr_t)(const __attribute__((address_space(3))) unsigned short*)p;
  bf16x8 r;
  asm volatile("ds_read_b128 %0, %1" : "=v"(r) : "v"(off));
  return r;
}

#define GLOAD16(g, l)                                                          \
  __builtin_amdgcn_global_load_lds(                                            \
      (const __attribute__((address_space(1))) void*)(g),                      \
      (__attribute__((address_space(3))) void*)(l), 16, 0, 0)

// ---------------- GroupNorm stats: per-sample sum / sumsq ----------------
__global__ __launch_bounds__(256) void k_gn_stats(const float* __restrict__ x,
                                                  float* __restrict__ stats) {
  int b = blockIdx.x >> 6, chunk = blockIdx.x & 63;
  const float4* xp = (const float4*)(x + ((size_t)b << 20) + (size_t)chunk * 16384);
  int t = threadIdx.x;
  float s = 0.f, q = 0.f;
#pragma unroll
  for (int i = 0; i < 16; ++i) {
    float4 v = xp[i * 256 + t];
    s += v.x + v.y + v.z + v.w;
    q += v.x * v.x + v.y * v.y + v.z * v.z + v.w * v.w;
  }
#pragma unroll
  for (int m = 1; m <= 32; m <<= 1) { s += __shfl_xor(s, m); q += __shfl_xor(q, m); }
  __shared__ float ls[8];
  int w = t >> 6, l = t & 63;
  if (l == 0) { ls[w * 2] = s; ls[w * 2 + 1] = q; }
  __syncthreads();
  if (t == 0) {
    float S = ls[0] + ls[2] + ls[4] + ls[6];
    float Q = ls[1] + ls[3] + ls[5] + ls[7];
    atomicAdd(&stats[b * 2], S);
    atomicAdd(&stats[b * 2 + 1], Q);
  }
}

// ---------- normalize + NCHW->padded-NHWC transpose (bf16) ----------
__global__ __launch_bounds__(256) void k_gn_norm(const float* __restrict__ x,
                                                 const float* __restrict__ stats,
                                                 const float* __restrict__ g,
                                                 const float* __restrict__ bb,
                                                 unsigned short* __restrict__ xnp) {
  __shared__ float tile[64][65];
  int pt = blockIdx.x;  // image row y (64 pixels)
  int ct = blockIdx.y;  // ci tile (4)
  int b = blockIdx.z;
  int t = threadIdx.x, tr = t >> 6, tc = t & 63;
  const float* xb = x + ((size_t)b << 20) + (size_t)(ct * 64) * 4096 + pt * 64;
#pragma unroll
  for (int i = 0; i < 16; ++i) {
    int r = i * 4 + tr;
    tile[r][tc] = xb[(size_t)r * 4096 + tc];
  }
  __syncthreads();
  float mu = stats[b * 2] * (1.f / 1048576.f);
  float var = stats[b * 2 + 1] * (1.f / 1048576.f) - mu * mu;
  float istd = rsqrtf(var + EPSV);
  float gg = g[ct * 64 + tc] * istd;
  float bv = bb[ct * 64 + tc];
  unsigned short* out = xnp + (((size_t)b * 66 + (pt + 1)) * 66 + 1) * 256 + ct * 64 + tc;
#pragma unroll
  for (int i = 0; i < 16; ++i) {
    int pcol = i * 4 + tr;
    float v = (tile[tc][pcol] - mu) * gg + bv;
    out[(size_t)pcol * 256] = f2bf(v);
  }
}

// ------------- weight prep: w_in -> wt[tap][co][ci] bf16, BN folded -------------
__global__ __launch_bounds__(256) void k_prep_wt(const float* __restrict__ w_in,
                                                 const float* __restrict__ bg,
                                                 const float* __restrict__ bv,
                                                 unsigned short* __restrict__ wt) {
  int idx = blockIdx.x * 256 + threadIdx.x;
  if (idx >= 9 * 384 * 256) return;
  int tap = idx / 98304;
  int rem = idx - tap * 98304;
  int co = rem >> 8, ci = rem & 255;
  float s = bg[co] * rsqrtf(bv[co] + EPSV);
  wt[idx] = f2bf(w_in[(size_t)(co * 256 + ci) * 9 + tap] * s);
}

__global__ __launch_bounds__(256) void k_prep_misc(
    const float* w_out, const float* og, const float* ob, const float* om, const float* ov,
    const float* big, const float* bib, const float* bim, const float* biv,
    const float* w_k, const float* kg, const float* kb, const float* km, const float* kvv,
    const float* w_v, const float* vg, const float* vb, const float* vm, const float* vvv,
    unsigned short* wo2, float* bias_in, float* bias_out,
    float* wkf, float* bias_k, float* wvf, float* bias_v) {
  int idx = blockIdx.x * 256 + threadIdx.x;
  if (idx < 65536) {
    int co = idx >> 8;
    float s = og[co] * rsqrtf(ov[co] + EPSV);
    wo2[idx] = f2bf(w_out[idx] * s);
    return;
  }
  idx -= 65536;
  if (idx < 384) {
    float s = big[idx] * rsqrtf(biv[idx] + EPSV);
    bias_in[idx] = bib[idx] - bim[idx] * s;
    return;
  }
  idx -= 384;
  if (idx < 256) {
    float s = og[idx] * rsqrtf(ov[idx] + EPSV);
    bias_out[idx] = ob[idx] - om[idx] * s;
    return;
  }
  idx -= 256;
  if (idx < 64) {
    float s = kg[idx] * rsqrtf(kvv[idx] + EPSV);
#pragma unroll
    for (int tp = 0; tp < 4; ++tp) wkf[idx * 4 + tp] = w_k[idx * 4 + tp] * s;
    bias_k[idx] = kb[idx] - km[idx] * s;
    return;
  }
  idx -= 64;
  if (idx < 128) {
    float s = vg[idx] * rsqrtf(vvv[idx] + EPSV);
#pragma unroll
    for (int tp = 0; tp < 4; ++tp) wvf[idx * 4 + tp] = w_v[idx * 4 + tp] * s;
    bias_v[idx] = vb[idx] - vm[idx] * s;
    return;
  }
}

// ---------------- conv3x3 implicit GEMM, pipelined 128x192 tile, 2 blocks/CU ----------------
// y[b][p][co] bf16. BM=128, BN=192, BK=64, 256 thr (4 waves 2Mx2N, 64x96/wave).
// LDS 80KB dbuf -> exactly 2 blocks/CU (cross-block overlap at barriers).
// Counted vmcnt(10); src-side XOR swizzle; split-k2 ds_read with lgkmcnt(10).
__global__ __launch_bounds__(256, 2) void k_conv3(const unsigned short* __restrict__ xnp,
                                                  const unsigned short* __restrict__ wt,
                                                  const float* __restrict__ bias_in,
                                                  unsigned short* __restrict__ y) {
  __shared__ alignas(16) unsigned short As[2][128 * 64];
  __shared__ alignas(16) unsigned short Bs[2][192 * 64];
  int pt = blockIdx.x, cot = blockIdx.y, b = blockIdx.z;
  int p0 = pt * 128, co0 = cot * 192;
  int t = threadIdx.x, w = t >> 6, l = t & 63;
  int lg = l >> 4, lr = l & 15;
  int wrM = (w >> 1) * 64, wrN = (w & 1) * 96;

  // staging: slot = i*256 + t (16B each); row = slot>>3; physical chunk = t&7;
  // logical chunk = (t&7) ^ (row&7); row&7 == (t>>3)&7 since i*256 % (8*8) == 0
  int lchunk = (t & 7) ^ ((t >> 3) & 7);
  int abase[4];
#pragma unroll
  for (int i = 0; i < 4; ++i) {
    int row = i * 32 + (t >> 3);
    int p = p0 + row;
    int yy = p >> 6, xx = p & 63;
    abase[i] = ((b * 66 + yy) * 66 + xx) * 256 + lchunk * 8;
  }
  int bbase[6];
#pragma unroll
  for (int i = 0; i < 6; ++i) {
    int row = i * 32 + (t >> 3);
    bbase[i] = (co0 + row) * 256 + lchunk * 8;
  }

  f32x4 acc[4][6];
#pragma unroll
  for (int i = 0; i < 4; ++i)
#pragma unroll
    for (int j = 0; j < 6; ++j) acc[i][j] = f32x4{0.f, 0.f, 0.f, 0.f};

#define STAGE(step, buf)                                                       \
  do {                                                                         \
    int tap_ = (step) >> 2, kc_ = (step) & 3;                                  \
    int dy_ = (tap_ * 11) >> 5;                                                \
    int dx_ = tap_ - dy_ * 3;                                                  \
    int aoff_ = (dy_ * 66 + dx_) * 256 + kc_ * 64;                             \
    int boff_ = tap_ * 98304 + kc_ * 64;                                       \
    _Pragma("unroll")                                                          \
    for (int i_ = 0; i_ < 4; ++i_)                                             \
      GLOAD16(xnp + abase[i_] + aoff_, &As[buf][(i_ * 256 + t) * 8]);          \
    _Pragma("unroll")                                                          \
    for (int i_ = 0; i_ < 6; ++i_)                                             \
      GLOAD16(wt + bbase[i_] + boff_, &Bs[buf][(i_ * 256 + t) * 8]);           \
  } while (0)

  STAGE(0, 0);

  for (int step = 0; step < 36; ++step) {
    int cur = step & 1;
    asm volatile("" ::: "memory");  // pin STAGE below the previous barrier
    if (step < 35) {
      STAGE(step + 1, cur ^ 1);
      asm volatile("s_waitcnt vmcnt(10)" ::: "memory");
    } else {
      asm volatile("s_waitcnt vmcnt(0)" ::: "memory");
    }
    __builtin_amdgcn_s_barrier();
    __builtin_amdgcn_sched_barrier(0);

    const unsigned short* Ac = As[cur];
    const unsigned short* Bc = Bs[cur];

    bf16x8 bfr[2][6], afr[2][4];
#pragma unroll
    for (int k2 = 0; k2 < 2; ++k2) {
#pragma unroll
      for (int nt = 0; nt < 6; ++nt) {
        int row = wrN + nt * 16 + lr;
        bfr[k2][nt] = dsread16(&Bc[row * 64 + (((k2 * 4 + lg) ^ (row & 7)) * 8)]);
      }
#pragma unroll
      for (int mt = 0; mt < 4; ++mt) {
        int row = wrM + mt * 16 + lr;
        afr[k2][mt] = dsread16(&Ac[row * 64 + (((k2 * 4 + lg) ^ (row & 7)) * 8)]);
      }
    }
    asm volatile("s_waitcnt lgkmcnt(10)" ::: "memory");
    __builtin_amdgcn_sched_barrier(0);
    __builtin_amdgcn_s_setprio(1);
#pragma unroll
    for (int mt = 0; mt < 4; ++mt)
#pragma unroll
      for (int nt = 0; nt < 6; ++nt)
        acc[mt][nt] = mfma16(afr[0][mt], bfr[0][nt], acc[mt][nt]);
    __builtin_amdgcn_s_setprio(0);
    asm volatile("s_waitcnt lgkmcnt(0)" ::: "memory");
    __builtin_amdgcn_sched_barrier(0);
    __builtin_amdgcn_s_setprio(1);
#pragma unroll
    for (int mt = 0; mt < 4; ++mt)
#pragma unroll
      for (int nt = 0; nt < 6; ++nt)
        acc[mt][nt] = mfma16(afr[1][mt], bfr[1][nt], acc[mt][nt]);
    __builtin_amdgcn_s_setprio(0);
    __builtin_amdgcn_sched_barrier(0);
    __builtin_amdgcn_s_barrier();
  }
#undef STAGE

  float bias[6];
#pragma unroll
  for (int nt = 0; nt < 6; ++nt) bias[nt] = bias_in[co0 + wrN + nt * 16 + lr];
#pragma unroll
  for (int mt = 0; mt < 4; ++mt) {
#pragma unroll
    for (int r = 0; r < 4; ++r) {
      int p = p0 + wrM + mt * 16 + lg * 4 + r;
      size_t rowoff = ((size_t)(b * 4096 + p)) * 384;
#pragma unroll
      for (int nt = 0; nt < 6; ++nt) {
        int co = co0 + wrN + nt * 16 + lr;
        float v = acc[mt][nt][r] + bias[nt];
        if (co >= 256) v = fmaxf(v, 0.f);  // pre-ReLU the u channels
        y[rowoff + co] = f2bf(v);
      }
    }
  }
}

// ------------- depthwise 2x2 stride-2 convs, LDS-tiled -------------
__global__ __launch_bounds__(256) void k_kv(const unsigned short* __restrict__ y,
                                            const float* __restrict__ wkf, const float* __restrict__ bias_k,
                                            const float* __restrict__ wvf, const float* __restrict__ bias_v,
                                            unsigned short* __restrict__ kk, unsigned short* __restrict__ vv) {
  constexpr int LDW = 200;
  __shared__ unsigned short ty[128 * LDW];
  __shared__ unsigned short vt[128 * 33];
  int b = blockIdx.x >> 5, my = blockIdx.x & 31;
  int t = threadIdx.x;
  const unsigned short* ybase = y + ((size_t)(b * 4096 + my * 128)) * 384 + 64;
#pragma unroll
  for (int j = 0; j < 12; ++j) {
    int idx = j * 256 + t;
    int row = idx / 24, c8 = idx - row * 24;
    bf16x8 v = *(const bf16x8*)&ybase[(size_t)row * 384 + c8 * 8];
    *(bf16x8*)&ty[row * LDW + c8 * 8] = v;
  }
  __syncthreads();

  {
    int c = t & 63, wq = t >> 6;
    float wk0 = wkf[c * 4 + 0], wk1 = wkf[c * 4 + 1];
    float wk2 = wkf[c * 4 + 2], wk3 = wkf[c * 4 + 3];
    float bk = bias_k[c];
#pragma unroll
    for (int pass = 0; pass < 8; ++pass) {
      int mx = pass * 4 + wq;
      int r0 = 2 * mx, r1 = 2 * mx + 1;
      float a = bk;
      a += bf2f(ty[r0 * LDW + c]) * wk0;
      a += bf2f(ty[(r0 + 1) * LDW + c]) * wk1;
      a += bf2f(ty[(64 + r0) * LDW + c]) * wk2;
      a += bf2f(ty[(64 + r1) * LDW + c]) * wk3;
      kk[((size_t)(b * 1024 + my * 32 + mx)) * 64 + c] = f2bf(a);
    }
  }

  {
    int cv = t & 127, mxh = t >> 7;
    float wv0 = wvf[cv * 4 + 0], wv1 = wvf[cv * 4 + 1];
    float wv2 = wvf[cv * 4 + 2], wv3 = wvf[cv * 4 + 3];
    float bv = bias_v[cv];
    int col = 64 + cv;
#pragma unroll
    for (int pass = 0; pass < 16; ++pass) {
      int mx = pass * 2 + mxh;
      int r0 = 2 * mx, r1 = 2 * mx + 1;
      float a = bv;
      a += bf2f(ty[r0 * LDW + col]) * wv0;
      a += bf2f(ty[r1 * LDW + col]) * wv1;
      a += bf2f(ty[(64 + r0) * LDW + col]) * wv2;
      a += bf2f(ty[(64 + r1) * LDW + col]) * wv3;
      vt[cv * 33 + mx] = f2bf(a);
    }
  }
  __syncthreads();
  {
    int mx = t & 31, cvq = t >> 5;
#pragma unroll
    for (int i = 0; i < 16; ++i) {
      int cv = i * 8 + cvq;
      vv[((size_t)(b * 128 + cv)) * 1024 + my * 32 + mx] = vt[cv * 33 + mx];
    }
  }
}

// ---------------- flash attention (8 waves, 16 q/wave, K staged in LDS) ----------------
// writes relu(o) into y channels 128..255
__global__ __launch_bounds__(512, 4) void k_attn(unsigned short* __restrict__ y,
                                                 const unsigned short* __restrict__ kk,
                                                 const unsigned short* __restrict__ vvb) {
  __shared__ alignas(16) unsigned short Ks[2][4096];   // [64 key][64 ch], src-swizzled
  __shared__ alignas(16) unsigned short PT[8][64][16]; // per-wave [key][q]
  int blk = blockIdx.x;
  int b = blk >> 5, ntile = blk & 31;
  int t = threadIdx.x, w = t >> 6, l = t & 63;
  int lg = l >> 4, lr = l & 15;
  int nq0 = ntile * 128 + w * 16;
  const float SC = 0.125f * 1.44269504f;  // scale * log2(e)

  union { short8 s; bf16x8 b; } uo;
#pragma unroll
  for (int i = 0; i < 8; ++i) uo.s[i] = (short)0x3F80;  // bf16 1.0
  bf16x8 ones = uo.b;

  // Q fragment: 16 rows (queries), K=64
  bf16x8 qf[2];
#pragma unroll
  for (int c = 0; c < 2; ++c)
    qf[c] = *(const bf16x8*)&y[((size_t)(b * 4096 + nq0 + lr)) * 384 + c * 32 + lg * 8];

  f32x4 oa[8];
#pragma unroll
  for (int tt = 0; tt < 8; ++tt) oa[tt] = f32x4{0.f, 0.f, 0.f, 0.f};
  float mi[4], li[4];
#pragma unroll
  for (int r = 0; r < 4; ++r) { mi[r] = -1e30f; li[r] = 0.f; }

  // K staging: thread t covers key row t>>3, 16B chunk (t&7), source-side XOR swizzle
  int srow = t >> 3;
  int skg = (t & 7) ^ (srow & 7);
  const unsigned short* ksrc = kk + ((size_t)(b * 1024 + srow)) * 64 + skg * 8;
  unsigned short* ldst0 = &Ks[0][w * 512];
  unsigned short* ldst1 = &Ks[1][w * 512];

  GLOAD16(ksrc, ldst0);
  __syncthreads();

  for (int it = 0; it < 16; ++it) {
    int cur = it & 1;
    const unsigned short* Kc = &Ks[cur][0];
    if (it < 15) GLOAD16(ksrc + (it + 1) * 4096, cur ? ldst0 : ldst1);

    // ---- QK^T: s[mt][r] = S[q=lg*4+r][key=mt*16+lr] (raw) ----
    f32x4 s[4];
#pragma unroll
    for (int mt = 0; mt < 4; ++mt) {
      int row = mt * 16 + lr;
      int sw = (lr & 7) << 3;
      bf16x8 kf0 = *(const bf16x8*)&Kc[row * 64 + ((lg * 8) ^ sw)];
      bf16x8 kf1 = *(const bf16x8*)&Kc[row * 64 + ((32 + lg * 8) ^ sw)];
      f32x4 z = f32x4{0.f, 0.f, 0.f, 0.f};
      z = mfma16(qf[0], kf0, z);
      z = mfma16(qf[1], kf1, z);
      s[mt] = z;
    }

    // ---- online softmax (scaled into exp2 domain) ----
    float rm[4];
#pragma unroll
    for (int r = 0; r < 4; ++r)
      rm[r] = fmaxf(fmaxf(s[0][r], s[1][r]), fmaxf(s[2][r], s[3][r]));
#pragma unroll
    for (int msk = 1; msk <= 8; msk <<= 1)
#pragma unroll
      for (int r = 0; r < 4; ++r) rm[r] = fmaxf(rm[r], __shfl_xor(rm[r], msk));
    bool grow = false;
#pragma unroll
    for (int r = 0; r < 4; ++r) grow |= (rm[r] * SC > mi[r]);
    if (__any(grow)) {
#pragma unroll
      for (int r = 0; r < 4; ++r) {
        float nm = fmaxf(mi[r], rm[r] * SC);
        float corr = exp2f(mi[r] - nm);
        mi[r] = nm;
        li[r] *= corr;
#pragma unroll
        for (int tt = 0; tt < 8; ++tt) oa[tt][r] *= corr;
      }
    }
#pragma unroll
    for (int mt = 0; mt < 4; ++mt)
#pragma unroll
      for (int r = 0; r < 4; ++r)
        s[mt][r] = exp2f(fmaf(s[mt][r], SC, -mi[r]));

    // ---- P -> P_T[key][q] packed writes (4 queries contiguous per lane) ----
#pragma unroll
    for (int mt = 0; mt < 4; ++mt) {
      unsigned p01 = cvt_pk_bf16(s[mt][0], s[mt][1]);
      unsigned p23 = cvt_pk_bf16(s[mt][2], s[mt][3]);
      unsigned long long pk = ((unsigned long long)p23 << 32) | p01;
      *(unsigned long long*)&PT[w][mt * 16 + lr][lg * 4] = pk;
    }
    asm volatile("s_waitcnt lgkmcnt(0)" ::: "memory");

    // ---- transpose-read P as A-fragments: lane holds P[q=lr][key=kc*32+lg*8+j] ----
    bf16x8 pf[2];
#pragma unroll
    for (int kc = 0; kc < 2; ++kc) {
      unsigned base = (unsigned)(uintptr_t)&PT[w][kc * 32 + lg * 8][lr];
      uint2 t0, t1;
      asm volatile("ds_read_b64_tr_b16 %0, %1" : "=v"(t0) : "v"(base));
      asm volatile("ds_read_b64_tr_b16 %0, %1 offset:128" : "=v"(t1) : "v"(base));
      union { unsigned u[4]; bf16x8 b; } cv;
      cv.u[0] = t0.x; cv.u[1] = t0.y; cv.u[2] = t1.x; cv.u[3] = t1.y;
      pf[kc] = cv.b;
    }
    asm volatile("s_waitcnt lgkmcnt(0)" ::: "memory");
    __builtin_amdgcn_sched_barrier(0);

    // ---- row sums via MFMA against ones (consistent with bf16 P) ----
    {
      f32x4 zz = f32x4{0.f, 0.f, 0.f, 0.f};
      zz = mfma16(pf[0], ones, zz);
      zz = mfma16(pf[1], ones, zz);
#pragma unroll
      for (int r = 0; r < 4; ++r) li[r] += zz[r];
    }

    // ---- PV: oa[tt] += P x V ----
    size_t vbase = ((size_t)(b * 128)) * 1024 + it * 64 + lg * 8;
#pragma unroll
    for (int tt = 0; tt < 8; ++tt) {
      const unsigned short* vr = &vvb[vbase + (size_t)(tt * 16 + lr) * 1024];
      bf16x8 vf0 = *(const bf16x8*)&vr[0];
      bf16x8 vf1 = *(const bf16x8*)&vr[32];
      oa[tt] = mfma16(pf[0], vf0, oa[tt]);
      oa[tt] = mfma16(pf[1], vf1, oa[tt]);
    }
    __syncthreads();
  }

#pragma unroll
  for (int r = 0; r < 4; ++r) {
    float inv = 1.f / li[r];
    int p = nq0 + lg * 4 + r;
    size_t rowoff = ((size_t)(b * 4096 + p)) * 384 + 128;
#pragma unroll
    for (int tt = 0; tt < 8; ++tt) {
      float v = oa[tt][r] * inv;
      v = fmaxf(v, 0.f);  // pre-ReLU for conv1x1
      y[rowoff + tt * 16 + lr] = f2bf(v);
    }
  }
}

// ---------------- conv1x1 GEMM: out[b][co][p] f32 (NCHW) ----------------
__global__ __launch_bounds__(256) void k_conv1(const unsigned short* __restrict__ y,
                                               const unsigned short* __restrict__ wo2,
                                               const float* __restrict__ bias_out,
                                               float* __restrict__ out) {
  int ptile = blockIdx.x, cot = blockIdx.y, b = blockIdx.z;
  int p0 = ptile * 128, co0 = cot * 128;
  __shared__ alignas(16) unsigned short As[128 * 64];
  __shared__ alignas(16) unsigned short Bs[128 * 64];
  int t = threadIdx.x, w = t >> 6, l = t & 63;
  int rr = t >> 3, c8 = (t & 7) * 8;
  int lg = l >> 4, lr = l & 15;
  int baseA = (co0 + rr) * 256 + c8;
  size_t baseB = ((size_t)(b * 4096 + p0 + rr)) * 384 + 128 + c8;
  f32x4 acc[4][4];
#pragma unroll
  for (int i = 0; i < 4; ++i)
#pragma unroll
    for (int j = 0; j < 4; ++j) acc[i][j] = f32x4{0.f, 0.f, 0.f, 0.f};
  int wr = (w >> 1) * 64, wc = (w & 1) * 64;
#pragma unroll 1
  for (int kc = 0; kc < 4; ++kc) {
    int ci0 = kc * 64;
    __syncthreads();
#pragma unroll
    for (int i = 0; i < 4; ++i) {
      GLOAD16(wo2 + baseA + i * 8192 + ci0, &As[(i * 32 + w * 8) * 64]);
      GLOAD16(y + baseB + (size_t)i * 32 * 384 + ci0, &Bs[(i * 32 + w * 8) * 64]);
    }
    __syncthreads();
    bf16x8 af[4][2], bf[4][2];
#pragma unroll
    for (int mt = 0; mt < 4; ++mt)
#pragma unroll
      for (int k2 = 0; k2 < 2; ++k2) {
        af[mt][k2] = *(const bf16x8*)&As[(wr + mt * 16 + lr) * 64 + k2 * 32 + lg * 8];
        bf[mt][k2] = *(const bf16x8*)&Bs[(wc + mt * 16 + lr) * 64 + k2 * 32 + lg * 8];
      }
#pragma unroll
    for (int mt = 0; mt < 4; ++mt)
#pragma unroll
      for (int nt = 0; nt < 4; ++nt) {
        acc[mt][nt] = mfma16(af[mt][0], bf[nt][0], acc[mt][nt]);
        acc[mt][nt] = mfma16(af[mt][1], bf[nt][1], acc[mt][nt]);
      }
  }
#pragma unroll
  for (int mt = 0; mt < 4; ++mt)
#pragma unroll
    for (int r = 0; r < 4; ++r) {
      int co = co0 + wr + mt * 16 + lg * 4 + r;
      float bv = bias_out[co];
      size_t obase = ((size_t)(b * 256 + co)) << 12;
#pragma unroll
      for (int nt = 0; nt < 4; ++nt) {
        int p = p0 + wc + nt * 16 + lr;
        out[obase + p] = acc[mt][nt][r] + bv;
      }
    }
}

// ---------------- host launch ----------------
static constexpr size_t pad256(size_t x) { return (x + 255) & ~(size_t)255; }

extern "C" void kernel_launch(void* const* d_in, const int* in_sizes, int n_in,
                              void* d_out, int out_size, void* d_ws, size_t ws_size,
                              hipStream_t stream) {
  const float* x      = (const float*)d_in[0];
  const float* gn_g   = (const float*)d_in[1];
  const float* gn_b   = (const float*)d_in[2];
  const float* w_in   = (const float*)d_in[3];
  const float* bin_g  = (const float*)d_in[4];
  const float* bin_b  = (const float*)d_in[5];
  const float* bin_m  = (const float*)d_in[6];
  const float* bin_v  = (const float*)d_in[7];
  const float* w_k    = (const float*)d_in[8];
  const float* bk_g   = (const float*)d_in[9];
  const float* bk_b   = (const float*)d_in[10];
  const float* bk_m   = (const float*)d_in[11];
  const float* bk_v   = (const float*)d_in[12];
  const float* w_v    = (const float*)d_in[13];
  const float* bv_g   = (const float*)d_in[14];
  const float* bv_b   = (const float*)d_in[15];
  const float* bv_m   = (const float*)d_in[16];
  const float* bv_v   = (const float*)d_in[17];
  const float* w_out  = (const float*)d_in[18];
  const float* bo_g   = (const float*)d_in[19];
  const float* bo_b   = (const float*)d_in[20];
  const float* bo_m   = (const float*)d_in[21];
  const float* bo_v   = (const float*)d_in[22];
  float* out = (float*)d_out;

  char* ws = (char*)d_ws;
  size_t off = 0;
  float*          stats   = (float*)(ws + off);          off += pad256(128);
  unsigned short* wt      = (unsigned short*)(ws + off); off += pad256((size_t)9 * 384 * 256 * 2);
  float*          bias_in = (float*)(ws + off);          off += pad256(384 * 4);
  unsigned short* wo2     = (unsigned short*)(ws + off); off += pad256(256 * 256 * 2);
  float*          bias_out= (float*)(ws + off);          off += pad256(256 * 4);
  float*          wkf     = (float*)(ws + off);          off += pad256(64 * 4 * 4);
  float*          bias_k  = (float*)(ws + off);          off += pad256(64 * 4);
  float*          wvf     = (float*)(ws + off);          off += pad256(128 * 4 * 4);
  float*          bias_v  = (float*)(ws + off);          off += pad256(128 * 4);
  unsigned short* xnp     = (unsigned short*)(ws + off); off += pad256((size_t)16 * 66 * 66 * 256 * 2);
  unsigned short* y       = (unsigned short*)(ws + off); off += pad256((size_t)16 * 4096 * 384 * 2);
  unsigned short* kk      = (unsigned short*)(ws + off); off += pad256((size_t)16 * 1024 * 64 * 2);
  unsigned short* vv      = (unsigned short*)(ws + off); off += pad256((size_t)16 * 128 * 1024 * 2);
  (void)ws_size; (void)out_size; (void)n_in; (void)in_sizes;

  hipMemsetAsync(stats, 0, 256, stream);
  hipMemsetAsync(xnp, 0, (size_t)16 * 66 * 66 * 256 * 2, stream);

  k_gn_stats<<<1024, 256, 0, stream>>>(x, stats);
  k_prep_wt<<<3456, 256, 0, stream>>>(w_in, bin_g, bin_v, wt);
  k_prep_misc<<<260, 256, 0, stream>>>(w_out, bo_g, bo_b, bo_m, bo_v,
                                       bin_g, bin_b, bin_m, bin_v,
                                       w_k, bk_g, bk_b, bk_m, bk_v,
                                       w_v, bv_g, bv_b, bv_m, bv_v,
                                       wo2, bias_in, bias_out, wkf, bias_k, wvf, bias_v);
  k_gn_norm<<<dim3(64, 4, 16), 256, 0, stream>>>(x, stats, gn_g, gn_b, xnp);
  k_conv3<<<dim3(32, 2, 16), 256, 0, stream>>>(xnp, wt, bias_in, y);
  k_kv<<<512, 256, 0, stream>>>(y, wkf, bias_k, wvf, bias_v, kk, vv);
  k_attn<<<512, 512, 0, stream>>>(y, kk, vv);
  k_conv1<<<dim3(32, 2, 16), 256, 0, stream>>>(y, wo2, bias_out, out);
}